// Round 1
// baseline (1153.447 us; speedup 1.0000x reference)
//
#include <hip/hip_runtime.h>
#include <hip/hip_bf16.h>
#include <math.h>

#define NF 256   // input features
#define NO 64    // heads*c1 = 8*8
#define NHEAD 8
#define NEG_SLOPE 0.2f

__device__ __forceinline__ float lrelu(float x) { return x > 0.f ? x : NEG_SLOPE * x; }

// ---------------------------------------------------------------------------
// K1: h1 = x @ W1  (50000x256 @ 256x64), fused alpha_src/alpha_dst per node.
// One wave per row; lane = output column (h = lane>>3, c = lane&7).
// W1 staged in LDS (64KB). 2 blocks/CU.
// ---------------------------------------------------------------------------
__global__ __launch_bounds__(256) void k_gemm1(
    const float* __restrict__ x, const float* __restrict__ W,
    const float* __restrict__ a_src, const float* __restrict__ a_dst,
    float* __restrict__ h1, float* __restrict__ as1, float* __restrict__ ad1,
    int N)
{
    __shared__ float Wl[NF * NO];  // 65536 bytes
    for (int i = threadIdx.x; i < NF * NO / 4; i += blockDim.x)
        ((float4*)Wl)[i] = ((const float4*)W)[i];
    __syncthreads();

    const int lane = threadIdx.x & 63;
    const int wid  = blockIdx.x * (blockDim.x >> 6) + (threadIdx.x >> 6);
    const int nw   = gridDim.x * (blockDim.x >> 6);
    const int c    = lane & 7;
    const int h    = lane >> 3;
    const float avs = a_src[lane];   // a_src1[h][c]
    const float avd = a_dst[lane];

    for (int row = wid; row < N; row += nw) {
        const float4* x4 = (const float4*)(x + (size_t)row * NF);
        float acc0 = 0.f, acc1 = 0.f, acc2 = 0.f, acc3 = 0.f;
        #pragma unroll
        for (int k4 = 0; k4 < NF / 4; ++k4) {
            float4 xv = x4[k4];
            acc0 = fmaf(xv.x, Wl[(k4 * 4 + 0) * NO + lane], acc0);
            acc1 = fmaf(xv.y, Wl[(k4 * 4 + 1) * NO + lane], acc1);
            acc2 = fmaf(xv.z, Wl[(k4 * 4 + 2) * NO + lane], acc2);
            acc3 = fmaf(xv.w, Wl[(k4 * 4 + 3) * NO + lane], acc3);
        }
        float acc = (acc0 + acc1) + (acc2 + acc3);
        h1[(size_t)row * NO + lane] = acc;
        // per-head reduce (over the 8 "c" lanes) for alpha_s / alpha_d
        float vs = acc * avs, vd = acc * avd;
        #pragma unroll
        for (int m = 1; m < 8; m <<= 1) {
            vs += __shfl_xor(vs, m);
            vd += __shfl_xor(vd, m);
        }
        if (c == 0) {
            as1[row * NHEAD + h] = vs;
            ad1[row * NHEAD + h] = vd;
        }
    }
}

// ---------------------------------------------------------------------------
// K2: in-degree histogram over dst (edges + self loops)
// ---------------------------------------------------------------------------
__global__ void k_hist(const int* __restrict__ eidx, int E, int N,
                       unsigned* __restrict__ counts)
{
    int i = blockIdx.x * blockDim.x + threadIdx.x;
    int tot = E + N;
    if (i >= tot) return;
    int d = (i < E) ? eidx[E + i] : (i - E);
    atomicAdd(&counts[d], 1u);
}

// ---------------------------------------------------------------------------
// K3: exclusive scan of counts -> offs[0..N], cursor[i] = offs[i]
// Single block, 1024 threads, chunked.
// ---------------------------------------------------------------------------
__global__ __launch_bounds__(1024) void k_scan(
    const unsigned* __restrict__ counts, unsigned* __restrict__ offs,
    unsigned* __restrict__ cursor, int N)
{
    __shared__ unsigned wsum[16], wpre[16];
    __shared__ unsigned sbase, stot;
    if (threadIdx.x == 0) sbase = 0;
    __syncthreads();
    const int lane = threadIdx.x & 63;
    const int w    = threadIdx.x >> 6;
    for (int start = 0; start < N; start += 1024) {
        int i = start + (int)threadIdx.x;
        unsigned v = (i < N) ? counts[i] : 0u;
        unsigned p = v;
        #pragma unroll
        for (int d = 1; d < 64; d <<= 1) {
            unsigned t = __shfl_up(p, d);
            if (lane >= d) p += t;
        }
        if (lane == 63) wsum[w] = p;
        __syncthreads();
        if (threadIdx.x == 0) {
            unsigned r = 0;
            for (int j = 0; j < 16; ++j) { wpre[j] = r; r += wsum[j]; }
            stot = r;
        }
        __syncthreads();
        if (i < N) {
            unsigned incl = sbase + wpre[w] + p;  // inclusive prefix
            offs[i + 1] = incl;
            cursor[i]   = incl - v;
        }
        __syncthreads();
        if (threadIdx.x == 0) sbase += stot;
        __syncthreads();
    }
    if (threadIdx.x == 0) offs[0] = 0;
}

// ---------------------------------------------------------------------------
// K4: scatter edges into CSR (by dst). Order within a segment is arbitrary —
// only affects fp32 summation order, well below tolerance.
// ---------------------------------------------------------------------------
__global__ void k_fill(const int* __restrict__ eidx, int E, int N,
                       unsigned* __restrict__ cursor, int* __restrict__ csr)
{
    int i = blockIdx.x * blockDim.x + threadIdx.x;
    int tot = E + N;
    if (i >= tot) return;
    int s = (i < E) ? eidx[i]     : (i - E);
    int d = (i < E) ? eidx[E + i] : (i - E);
    unsigned pos = atomicAdd(&cursor[d], 1u);
    csr[pos] = s;
}

// ---------------------------------------------------------------------------
// K5: layer-1 GAT aggregation, one wave per dst node.
// lane = (h,c) output slot. Two passes over in-edges:
//   A) m_h = max_s alpha_s[s][h]        (8 edge slots in parallel)
//   B) denom_h += p, acc += p*h1[s][:]  (all lanes walk edges together)
// Epilogue: out = relu(acc/denom + b1); h2[n] = out . W2 (wave reduce).
// ---------------------------------------------------------------------------
__global__ __launch_bounds__(256) void k_gat1(
    const unsigned* __restrict__ offs, const int* __restrict__ csr,
    const float* __restrict__ h1, const float* __restrict__ as1,
    const float* __restrict__ ad1, const float* __restrict__ b1,
    const float* __restrict__ W2, float* __restrict__ h2, int N)
{
    const int lane = threadIdx.x & 63;
    const int n = blockIdx.x * (blockDim.x >> 6) + (threadIdx.x >> 6);
    if (n >= N) return;
    const int h = lane >> 3, c = lane & 7;
    const unsigned s0 = offs[n], s1 = offs[n + 1];
    const float ad = ad1[n * NHEAD + h];

    // pass A: segment max of alpha_s (8 parallel edge slots per head)
    float m = -INFINITY;
    for (unsigned j = s0 + (unsigned)c; j < s1; j += 8) {
        int s = csr[j];
        m = fmaxf(m, as1[s * NHEAD + h]);
    }
    m = fmaxf(m, __shfl_xor(m, 1));
    m = fmaxf(m, __shfl_xor(m, 2));
    m = fmaxf(m, __shfl_xor(m, 4));
    const float me = lrelu(m + ad);  // == segment max of e (lrelu monotone)

    // pass B: weighted accumulate
    float acc = 0.f, den = 0.f;
    for (unsigned j = s0; j < s1; ++j) {
        int s = __builtin_amdgcn_readfirstlane(csr[j]);
        float e = lrelu(as1[s * NHEAD + h] + ad);
        float p = __expf(e - me);
        den += p;
        acc = fmaf(p, h1[(size_t)s * NO + lane], acc);
    }
    float outv = fmaxf(acc / den + b1[lane], 0.f);  // +bias, ReLU

    // fused layer-2 projection: h2[n] = sum_l outv_l * W2_l
    float t = outv * W2[lane];
    #pragma unroll
    for (int msk = 1; msk < 64; msk <<= 1) t += __shfl_xor(t, msk);
    if (lane == 0) h2[n] = t;
}

// ---------------------------------------------------------------------------
// K6: layer-2 GAT (1 head, scalar channel) + global mean-pool accumulate.
// One wave per dst node; lanes stride over in-edges.
// ---------------------------------------------------------------------------
__global__ __launch_bounds__(256) void k_gat2(
    const unsigned* __restrict__ offs, const int* __restrict__ csr,
    const float* __restrict__ h2, const int* __restrict__ batch,
    const float* __restrict__ a_src2, const float* __restrict__ a_dst2,
    const float* __restrict__ b2,
    float* __restrict__ gsum, float* __restrict__ gcnt, int N)
{
    const int lane = threadIdx.x & 63;
    const int n = blockIdx.x * (blockDim.x >> 6) + (threadIdx.x >> 6);
    if (n >= N) return;
    const float aS = a_src2[0], aD = a_dst2[0];
    const unsigned s0 = offs[n], s1 = offs[n + 1];
    const float ad = h2[n] * aD;

    float m = -INFINITY;
    for (unsigned j = s0 + (unsigned)lane; j < s1; j += 64)
        m = fmaxf(m, h2[csr[j]] * aS);
    #pragma unroll
    for (int msk = 1; msk < 64; msk <<= 1) m = fmaxf(m, __shfl_xor(m, msk));
    const float me = lrelu(m + ad);

    float num = 0.f, den = 0.f;
    for (unsigned j = s0 + (unsigned)lane; j < s1; j += 64) {
        float hs = h2[csr[j]];
        float p = __expf(lrelu(hs * aS + ad) - me);
        num = fmaf(p, hs, num);
        den += p;
    }
    #pragma unroll
    for (int msk = 1; msk < 64; msk <<= 1) {
        num += __shfl_xor(num, msk);
        den += __shfl_xor(den, msk);
    }
    if (lane == 0) {
        float o = num / den + b2[0];
        int g = batch[n];
        unsafeAtomicAdd(&gsum[g], o);
        unsafeAtomicAdd(&gcnt[g], 1.0f);
    }
}

// ---------------------------------------------------------------------------
// K7: final per-graph mean
// ---------------------------------------------------------------------------
__global__ void k_final(const float* __restrict__ gsum,
                        const float* __restrict__ gcnt,
                        float* __restrict__ out, int G)
{
    int g = blockIdx.x * blockDim.x + threadIdx.x;
    if (g < G) out[g] = gsum[g] / fmaxf(gcnt[g], 1.0f);
}

// ---------------------------------------------------------------------------
extern "C" void kernel_launch(void* const* d_in, const int* in_sizes, int n_in,
                              void* d_out, int out_size, void* d_ws, size_t ws_size,
                              hipStream_t stream)
{
    const float* x      = (const float*)d_in[0];
    const int*   eidx   = (const int*)d_in[1];
    const int*   batch  = (const int*)d_in[2];
    const float* W1     = (const float*)d_in[3];
    const float* a_src1 = (const float*)d_in[4];
    const float* a_dst1 = (const float*)d_in[5];
    const float* b1     = (const float*)d_in[6];
    const float* W2     = (const float*)d_in[7];
    const float* a_src2 = (const float*)d_in[8];
    const float* a_dst2 = (const float*)d_in[9];
    const float* b2     = (const float*)d_in[10];

    const int N = in_sizes[0] / NF;      // 50000
    const int E = in_sizes[1] / 2;       // 1600000
    const int G = out_size;              // 64
    const int ETOT = E + N;

    // workspace layout (bytes)
    char* w = (char*)d_ws;
    float*    h1     = (float*)(w + 0);            // 12,800,000
    float*    as1    = (float*)(w + 12800000);     //  1,600,000
    float*    ad1    = (float*)(w + 14400000);     //  1,600,000
    float*    h2     = (float*)(w + 16000000);     //    200,000
    unsigned* counts = (unsigned*)(w + 16200000);  //    200,000
    unsigned* offs   = (unsigned*)(w + 16400000);  //    200,064
    unsigned* cursor = (unsigned*)(w + 16600064);  //    200,000
    int*      csr    = (int*)(w + 16800064);       //  6,600,000
    float*    gsum   = (float*)(w + 23400064);     //        256
    float*    gcnt   = (float*)(w + 23400320);     //        256

    hipMemsetAsync(counts, 0, (size_t)N * 4, stream);
    hipMemsetAsync(gsum, 0, 512, stream);  // gsum + gcnt

    k_gemm1<<<512, 256, 0, stream>>>(x, W1, a_src1, a_dst1, h1, as1, ad1, N);

    int eb = (ETOT + 255) / 256;
    k_hist<<<eb, 256, 0, stream>>>(eidx, E, N, counts);
    k_scan<<<1, 1024, 0, stream>>>(counts, offs, cursor, N);
    k_fill<<<eb, 256, 0, stream>>>(eidx, E, N, cursor, csr);

    k_gat1<<<(N + 3) / 4, 256, 0, stream>>>(offs, csr, h1, as1, ad1, b1, W2, h2, N);
    k_gat2<<<(N + 3) / 4, 256, 0, stream>>>(offs, csr, h2, batch, a_src2, a_dst2, b2,
                                            gsum, gcnt, N);
    k_final<<<1, 64, 0, stream>>>(gsum, gcnt, (float*)d_out, G);
}

// Round 2
// 753.676 us; speedup vs baseline: 1.5304x; 1.5304x over previous
//
#include <hip/hip_runtime.h>
#include <hip/hip_bf16.h>
#include <math.h>

#define NF 256   // input features
#define NO 64    // heads*c1 = 8*8
#define NHEAD 8
#define NEG_SLOPE 0.2f

__device__ __forceinline__ float lrelu(float x) { return x > 0.f ? x : NEG_SLOPE * x; }

// ---------------------------------------------------------------------------
// K1: h1 = x @ W1  (50000x256 @ 256x64), fused alpha_src/alpha_dst per node.
// One wave per row; lane = output column (h = lane>>3, c = lane&7).
// W1 staged in LDS (64KB). 2 blocks/CU.
// ---------------------------------------------------------------------------
__global__ __launch_bounds__(256) void k_gemm1(
    const float* __restrict__ x, const float* __restrict__ W,
    const float* __restrict__ a_src, const float* __restrict__ a_dst,
    float* __restrict__ h1, float* __restrict__ as1, float* __restrict__ ad1,
    int N)
{
    __shared__ float Wl[NF * NO];  // 65536 bytes
    for (int i = threadIdx.x; i < NF * NO / 4; i += blockDim.x)
        ((float4*)Wl)[i] = ((const float4*)W)[i];
    __syncthreads();

    const int lane = threadIdx.x & 63;
    const int wid  = blockIdx.x * (blockDim.x >> 6) + (threadIdx.x >> 6);
    const int nw   = gridDim.x * (blockDim.x >> 6);
    const int c    = lane & 7;
    const int h    = lane >> 3;
    const float avs = a_src[lane];   // a_src1[h][c]
    const float avd = a_dst[lane];

    for (int row = wid; row < N; row += nw) {
        const float4* x4 = (const float4*)(x + (size_t)row * NF);
        float acc0 = 0.f, acc1 = 0.f, acc2 = 0.f, acc3 = 0.f;
        #pragma unroll
        for (int k4 = 0; k4 < NF / 4; ++k4) {
            float4 xv = x4[k4];
            acc0 = fmaf(xv.x, Wl[(k4 * 4 + 0) * NO + lane], acc0);
            acc1 = fmaf(xv.y, Wl[(k4 * 4 + 1) * NO + lane], acc1);
            acc2 = fmaf(xv.z, Wl[(k4 * 4 + 2) * NO + lane], acc2);
            acc3 = fmaf(xv.w, Wl[(k4 * 4 + 3) * NO + lane], acc3);
        }
        float acc = (acc0 + acc1) + (acc2 + acc3);
        h1[(size_t)row * NO + lane] = acc;
        // per-head reduce (over the 8 "c" lanes) for alpha_s / alpha_d
        float vs = acc * avs, vd = acc * avd;
        #pragma unroll
        for (int m = 1; m < 8; m <<= 1) {
            vs += __shfl_xor(vs, m);
            vd += __shfl_xor(vd, m);
        }
        if (c == 0) {
            as1[row * NHEAD + h] = vs;
            ad1[row * NHEAD + h] = vd;
        }
    }
}

// ---------------------------------------------------------------------------
// K2: in-degree histogram over dst (edges + self loops)
// ---------------------------------------------------------------------------
__global__ void k_hist(const int* __restrict__ eidx, int E, int N,
                       unsigned* __restrict__ counts)
{
    int i = blockIdx.x * blockDim.x + threadIdx.x;
    int tot = E + N;
    if (i >= tot) return;
    int d = (i < E) ? eidx[E + i] : (i - E);
    atomicAdd(&counts[d], 1u);
}

// ---------------------------------------------------------------------------
// K3: exclusive scan of counts -> offs[0..N], cursor[i] = offs[i]
// ---------------------------------------------------------------------------
__global__ __launch_bounds__(1024) void k_scan(
    const unsigned* __restrict__ counts, unsigned* __restrict__ offs,
    unsigned* __restrict__ cursor, int N)
{
    __shared__ unsigned wsum[16], wpre[16];
    __shared__ unsigned sbase, stot;
    if (threadIdx.x == 0) sbase = 0;
    __syncthreads();
    const int lane = threadIdx.x & 63;
    const int w    = threadIdx.x >> 6;
    for (int start = 0; start < N; start += 1024) {
        int i = start + (int)threadIdx.x;
        unsigned v = (i < N) ? counts[i] : 0u;
        unsigned p = v;
        #pragma unroll
        for (int d = 1; d < 64; d <<= 1) {
            unsigned t = __shfl_up(p, d);
            if (lane >= d) p += t;
        }
        if (lane == 63) wsum[w] = p;
        __syncthreads();
        if (threadIdx.x == 0) {
            unsigned r = 0;
            for (int j = 0; j < 16; ++j) { wpre[j] = r; r += wsum[j]; }
            stot = r;
        }
        __syncthreads();
        if (i < N) {
            unsigned incl = sbase + wpre[w] + p;  // inclusive prefix
            offs[i + 1] = incl;
            cursor[i]   = incl - v;
        }
        __syncthreads();
        if (threadIdx.x == 0) sbase += stot;
        __syncthreads();
    }
    if (threadIdx.x == 0) offs[0] = 0;
}

// ---------------------------------------------------------------------------
// K4: scatter edges into CSR (by dst).
// ---------------------------------------------------------------------------
__global__ void k_fill(const int* __restrict__ eidx, int E, int N,
                       unsigned* __restrict__ cursor, int* __restrict__ csr)
{
    int i = blockIdx.x * blockDim.x + threadIdx.x;
    int tot = E + N;
    if (i >= tot) return;
    int s = (i < E) ? eidx[i]     : (i - E);
    int d = (i < E) ? eidx[E + i] : (i - E);
    unsigned pos = atomicAdd(&cursor[d], 1u);
    csr[pos] = s;
}

// ---------------------------------------------------------------------------
// K5: layer-1 GAT aggregation, one wave per dst node.
// Epilogue: out = relu(acc/denom + b1); h2[n] = out . W2 (wave reduce).
// ---------------------------------------------------------------------------
__global__ __launch_bounds__(256) void k_gat1(
    const unsigned* __restrict__ offs, const int* __restrict__ csr,
    const float* __restrict__ h1, const float* __restrict__ as1,
    const float* __restrict__ ad1, const float* __restrict__ b1,
    const float* __restrict__ W2, float* __restrict__ h2, int N)
{
    const int lane = threadIdx.x & 63;
    const int n = blockIdx.x * (blockDim.x >> 6) + (threadIdx.x >> 6);
    if (n >= N) return;
    const int h = lane >> 3, c = lane & 7;
    const unsigned s0 = offs[n], s1 = offs[n + 1];
    const float ad = ad1[n * NHEAD + h];

    // pass A: segment max of alpha_s (8 parallel edge slots per head)
    float m = -INFINITY;
    for (unsigned j = s0 + (unsigned)c; j < s1; j += 8) {
        int s = csr[j];
        m = fmaxf(m, as1[s * NHEAD + h]);
    }
    m = fmaxf(m, __shfl_xor(m, 1));
    m = fmaxf(m, __shfl_xor(m, 2));
    m = fmaxf(m, __shfl_xor(m, 4));
    const float me = lrelu(m + ad);  // == segment max of e (lrelu monotone)

    // pass B: weighted accumulate
    float acc = 0.f, den = 0.f;
    for (unsigned j = s0; j < s1; ++j) {
        int s = __builtin_amdgcn_readfirstlane(csr[j]);
        float e = lrelu(as1[s * NHEAD + h] + ad);
        float p = __expf(e - me);
        den += p;
        acc = fmaf(p, h1[(size_t)s * NO + lane], acc);
    }
    float outv = fmaxf(acc / den + b1[lane], 0.f);  // +bias, ReLU

    // fused layer-2 projection: h2[n] = sum_l outv_l * W2_l
    float t = outv * W2[lane];
    #pragma unroll
    for (int msk = 1; msk < 64; msk <<= 1) t += __shfl_xor(t, msk);
    if (lane == 0) h2[n] = t;
}

// ---------------------------------------------------------------------------
// K6: layer-2 GAT (1 head, scalar channel). Writes per-node output (NO
// contended atomics — that was 445µs of serialized cross-XCD line ping-pong).
// First gather iteration cached: avg degree 33 < 64 => single gather pass.
// ---------------------------------------------------------------------------
__global__ __launch_bounds__(256) void k_gat2(
    const unsigned* __restrict__ offs, const int* __restrict__ csr,
    const float* __restrict__ h2, const float* __restrict__ a_src2,
    const float* __restrict__ a_dst2, const float* __restrict__ b2,
    float* __restrict__ onode, int N)
{
    const int lane = threadIdx.x & 63;
    const int n = blockIdx.x * (blockDim.x >> 6) + (threadIdx.x >> 6);
    if (n >= N) return;
    const float aS = a_src2[0], aD = a_dst2[0];
    const unsigned s0 = offs[n], s1 = offs[n + 1];
    const float ad = h2[n] * aD;

    const unsigned j0 = s0 + (unsigned)lane;
    const bool has0 = (j0 < s1);
    float hs0 = 0.f;
    if (has0) hs0 = h2[csr[j0]];

    float m = has0 ? hs0 * aS : -INFINITY;
    for (unsigned j = j0 + 64; j < s1; j += 64)
        m = fmaxf(m, h2[csr[j]] * aS);
    #pragma unroll
    for (int msk = 1; msk < 64; msk <<= 1) m = fmaxf(m, __shfl_xor(m, msk));
    const float me = lrelu(m + ad);

    float num = 0.f, den = 0.f;
    if (has0) {
        float p = __expf(lrelu(hs0 * aS + ad) - me);
        num = p * hs0;
        den = p;
    }
    for (unsigned j = j0 + 64; j < s1; j += 64) {
        float hs = h2[csr[j]];
        float p = __expf(lrelu(hs * aS + ad) - me);
        num = fmaf(p, hs, num);
        den += p;
    }
    #pragma unroll
    for (int msk = 1; msk < 64; msk <<= 1) {
        num += __shfl_xor(num, msk);
        den += __shfl_xor(den, msk);
    }
    if (lane == 0) onode[n] = num / den + b2[0];
}

// ---------------------------------------------------------------------------
// K6b: mean-pool. batch is SORTED, so each wave of 64 consecutive nodes is
// (almost always) one graph: wave-reduce then ONE atomic pair per wave.
// ~1.7K atomics total instead of 100K.
// ---------------------------------------------------------------------------
__global__ __launch_bounds__(256) void k_pool(
    const float* __restrict__ onode, const int* __restrict__ batch,
    float* __restrict__ gsum, float* __restrict__ gcnt, int N)
{
    const int lane = threadIdx.x & 63;
    const int base = (blockIdx.x * (blockDim.x >> 6) + (threadIdx.x >> 6)) * 64;
    if (base >= N) return;
    const int n = base + lane;
    const bool act = (n < N);
    float o = 0.f;
    int g = -1;
    if (act) { o = onode[n]; g = batch[n]; }
    const int g0 = __shfl(g, 0);   // lane 0 always active (base < N)
    const bool same = (g == g0);
    float s = (act && same) ? o : 0.f;
    float c = (act && same) ? 1.f : 0.f;
    #pragma unroll
    for (int msk = 1; msk < 64; msk <<= 1) {
        s += __shfl_xor(s, msk);
        c += __shfl_xor(c, msk);
    }
    if (lane == 0) {
        unsafeAtomicAdd(&gsum[g0], s);
        unsafeAtomicAdd(&gcnt[g0], c);
    }
    if (act && !same) {            // graph boundary inside wave (rare: <64 waves)
        unsafeAtomicAdd(&gsum[g], o);
        unsafeAtomicAdd(&gcnt[g], 1.0f);
    }
}

// ---------------------------------------------------------------------------
// K7: final per-graph mean
// ---------------------------------------------------------------------------
__global__ void k_final(const float* __restrict__ gsum,
                        const float* __restrict__ gcnt,
                        float* __restrict__ out, int G)
{
    int g = blockIdx.x * blockDim.x + threadIdx.x;
    if (g < G) out[g] = gsum[g] / fmaxf(gcnt[g], 1.0f);
}

// ---------------------------------------------------------------------------
extern "C" void kernel_launch(void* const* d_in, const int* in_sizes, int n_in,
                              void* d_out, int out_size, void* d_ws, size_t ws_size,
                              hipStream_t stream)
{
    const float* x      = (const float*)d_in[0];
    const int*   eidx   = (const int*)d_in[1];
    const int*   batch  = (const int*)d_in[2];
    const float* W1     = (const float*)d_in[3];
    const float* a_src1 = (const float*)d_in[4];
    const float* a_dst1 = (const float*)d_in[5];
    const float* b1     = (const float*)d_in[6];
    const float* W2     = (const float*)d_in[7];
    const float* a_src2 = (const float*)d_in[8];
    const float* a_dst2 = (const float*)d_in[9];
    const float* b2     = (const float*)d_in[10];

    const int N = in_sizes[0] / NF;      // 50000
    const int E = in_sizes[1] / 2;       // 1600000
    const int G = out_size;              // 64
    const int ETOT = E + N;

    // workspace layout (bytes)
    char* w = (char*)d_ws;
    float*    h1     = (float*)(w + 0);            // 12,800,000
    float*    as1    = (float*)(w + 12800000);     //  1,600,000
    float*    ad1    = (float*)(w + 14400000);     //  1,600,000
    float*    h2     = (float*)(w + 16000000);     //    200,000
    unsigned* counts = (unsigned*)(w + 16200000);  //    200,000
    unsigned* offs   = (unsigned*)(w + 16400000);  //    200,064
    unsigned* cursor = (unsigned*)(w + 16600064);  //    200,000
    int*      csr    = (int*)(w + 16800064);       //  6,600,000
    float*    gsum   = (float*)(w + 23400064);     //        256
    float*    gcnt   = (float*)(w + 23400320);     //        256
    float*    onode  = (float*)(w + 23400576);     //    200,000

    hipMemsetAsync(counts, 0, (size_t)N * 4, stream);
    hipMemsetAsync(gsum, 0, 512, stream);  // gsum + gcnt

    k_gemm1<<<512, 256, 0, stream>>>(x, W1, a_src1, a_dst1, h1, as1, ad1, N);

    int eb = (ETOT + 255) / 256;
    k_hist<<<eb, 256, 0, stream>>>(eidx, E, N, counts);
    k_scan<<<1, 1024, 0, stream>>>(counts, offs, cursor, N);
    k_fill<<<eb, 256, 0, stream>>>(eidx, E, N, cursor, csr);

    k_gat1<<<(N + 3) / 4, 256, 0, stream>>>(offs, csr, h1, as1, ad1, b1, W2, h2, N);
    k_gat2<<<(N + 3) / 4, 256, 0, stream>>>(offs, csr, h2, a_src2, a_dst2, b2,
                                            onode, N);
    int pw = (N + 63) / 64;                       // one wave per 64 nodes
    k_pool<<<(pw + 3) / 4, 256, 0, stream>>>(onode, batch, gsum, gcnt, N);
    k_final<<<1, 64, 0, stream>>>(gsum, gcnt, (float*)d_out, G);
}

// Round 3
// 398.605 us; speedup vs baseline: 2.8937x; 1.8908x over previous
//
#include <hip/hip_runtime.h>
#include <hip/hip_bf16.h>
#include <math.h>

#define NF 256   // input features
#define NO 64    // heads*c1 = 8*8
#define NHEAD 8
#define NEG_SLOPE 0.2f
#define BM 64    // gemm row tile
#define KB 64    // gemm k tile
#define LS 68    // LDS row stride (floats), padded: +4 keeps b128 align, kills conflicts

__device__ __forceinline__ float lrelu(float x) { return x > 0.f ? x : NEG_SLOPE * x; }

// ---------------------------------------------------------------------------
// K1: h1 = x @ W1 (50000x256 @ 256x64) tiled GEMM + fused alpha_src/alpha_dst.
// 256 thr/block, block computes 64 rows x 64 cols; thread = 4x4 register tile.
// LDS: x tile [64][68] + W tile [64][68] = 34.8KB -> 4 blocks/CU.
// All global loads coalesced float4; LDS reads ds_read_b128 (<=2-way, free).
// ---------------------------------------------------------------------------
__global__ __launch_bounds__(256) void k_gemm1(
    const float* __restrict__ x, const float* __restrict__ W,
    const float* __restrict__ a_src, const float* __restrict__ a_dst,
    float* __restrict__ h1, float* __restrict__ as1, float* __restrict__ ad1,
    int N)
{
    __shared__ float xl[BM][LS];
    __shared__ float wl[KB][LS];
    const int t  = threadIdx.x;
    const int tx = t & 15;        // col group: cols 4*tx .. 4*tx+3
    const int ty = t >> 4;        // row group: rows 4*ty .. 4*ty+3
    const int row0 = blockIdx.x * BM;

    float acc[4][4] = {};

    for (int kc = 0; kc < NF; kc += KB) {
        // stage x tile: thread loads rows (t>>4)+16i, k-cols kc+4*tx (coalesced)
        #pragma unroll
        for (int i = 0; i < 4; ++i) {
            int r = (t >> 4) + 16 * i;
            int row = row0 + r; if (row >= N) row = N - 1;   // clamp, store-guarded later
            float4 v = *(const float4*)(x + (size_t)row * NF + kc + 4 * tx);
            *(float4*)&xl[r][4 * tx] = v;
        }
        // stage W tile: thread loads k=(t>>4)+16i, cols 4*tx (coalesced)
        #pragma unroll
        for (int i = 0; i < 4; ++i) {
            int k = (t >> 4) + 16 * i;
            float4 v = *(const float4*)(W + (size_t)(kc + k) * NO + 4 * tx);
            *(float4*)&wl[k][4 * tx] = v;
        }
        __syncthreads();

        #pragma unroll
        for (int k = 0; k < KB; k += 4) {
            float4 xv[4], wv[4];
            #pragma unroll
            for (int r = 0; r < 4; ++r)
                xv[r] = *(const float4*)&xl[4 * ty + r][k];      // 4 k's of row
            #pragma unroll
            for (int kk = 0; kk < 4; ++kk)
                wv[kk] = *(const float4*)&wl[k + kk][4 * tx];    // 4 cols of k
            #pragma unroll
            for (int r = 0; r < 4; ++r) {
                float4 xr = xv[r];
                #pragma unroll
                for (int kk = 0; kk < 4; ++kk) {
                    float xk = (kk == 0) ? xr.x : (kk == 1) ? xr.y : (kk == 2) ? xr.z : xr.w;
                    acc[r][0] = fmaf(xk, wv[kk].x, acc[r][0]);
                    acc[r][1] = fmaf(xk, wv[kk].y, acc[r][1]);
                    acc[r][2] = fmaf(xk, wv[kk].z, acc[r][2]);
                    acc[r][3] = fmaf(xk, wv[kk].w, acc[r][3]);
                }
            }
        }
        __syncthreads();
    }

    // epilogue: store h1 rows + per-head alpha reduce
    const float4 avs = *(const float4*)(a_src + 4 * tx);
    const float4 avd = *(const float4*)(a_dst + 4 * tx);
    #pragma unroll
    for (int r = 0; r < 4; ++r) {
        int row = row0 + 4 * ty + r;
        if (row >= N) continue;
        float4 o = make_float4(acc[r][0], acc[r][1], acc[r][2], acc[r][3]);
        *(float4*)(h1 + (size_t)row * NO + 4 * tx) = o;
        float vs = o.x * avs.x + o.y * avs.y + o.z * avs.z + o.w * avs.w;
        float vd = o.x * avd.x + o.y * avd.y + o.z * avd.z + o.w * avd.w;
        vs += __shfl_xor(vs, 1);   // tx pair (2j,2j+1) covers head j's 8 channels
        vd += __shfl_xor(vd, 1);
        if ((tx & 1) == 0) {
            as1[row * NHEAD + (tx >> 1)] = vs;
            ad1[row * NHEAD + (tx >> 1)] = vd;
        }
    }
}

// ---------------------------------------------------------------------------
// K2: in-degree histogram over dst (edges + self loops)
// ---------------------------------------------------------------------------
__global__ void k_hist(const int* __restrict__ eidx, int E, int N,
                       unsigned* __restrict__ counts)
{
    int i = blockIdx.x * blockDim.x + threadIdx.x;
    int tot = E + N;
    if (i >= tot) return;
    int d = (i < E) ? eidx[E + i] : (i - E);
    atomicAdd(&counts[d], 1u);
}

// ---------------------------------------------------------------------------
// K3: exclusive scan of counts -> offs[0..N], cursor[i] = offs[i]
// ---------------------------------------------------------------------------
__global__ __launch_bounds__(1024) void k_scan(
    const unsigned* __restrict__ counts, unsigned* __restrict__ offs,
    unsigned* __restrict__ cursor, int N)
{
    __shared__ unsigned wsum[16], wpre[16];
    __shared__ unsigned sbase, stot;
    if (threadIdx.x == 0) sbase = 0;
    __syncthreads();
    const int lane = threadIdx.x & 63;
    const int w    = threadIdx.x >> 6;
    for (int start = 0; start < N; start += 1024) {
        int i = start + (int)threadIdx.x;
        unsigned v = (i < N) ? counts[i] : 0u;
        unsigned p = v;
        #pragma unroll
        for (int d = 1; d < 64; d <<= 1) {
            unsigned t = __shfl_up(p, d);
            if (lane >= d) p += t;
        }
        if (lane == 63) wsum[w] = p;
        __syncthreads();
        if (threadIdx.x == 0) {
            unsigned r = 0;
            for (int j = 0; j < 16; ++j) { wpre[j] = r; r += wsum[j]; }
            stot = r;
        }
        __syncthreads();
        if (i < N) {
            unsigned incl = sbase + wpre[w] + p;  // inclusive prefix
            offs[i + 1] = incl;
            cursor[i]   = incl - v;
        }
        __syncthreads();
        if (threadIdx.x == 0) sbase += stot;
        __syncthreads();
    }
    if (threadIdx.x == 0) offs[0] = 0;
}

// ---------------------------------------------------------------------------
// K4: scatter edges into CSR (by dst).
// ---------------------------------------------------------------------------
__global__ void k_fill(const int* __restrict__ eidx, int E, int N,
                       unsigned* __restrict__ cursor, int* __restrict__ csr)
{
    int i = blockIdx.x * blockDim.x + threadIdx.x;
    int tot = E + N;
    if (i >= tot) return;
    int s = (i < E) ? eidx[i]     : (i - E);
    int d = (i < E) ? eidx[E + i] : (i - E);
    unsigned pos = atomicAdd(&cursor[d], 1u);
    csr[pos] = s;
}

// ---------------------------------------------------------------------------
// K5: layer-1 GAT aggregation, one wave per dst node. Pass B unrolled x4 so
// 4 independent 256B h1-gathers are in flight (latency hiding).
// Epilogue: out = relu(acc/denom + b1); h2[n] = out . W2 (wave reduce).
// ---------------------------------------------------------------------------
__global__ __launch_bounds__(256) void k_gat1(
    const unsigned* __restrict__ offs, const int* __restrict__ csr,
    const float* __restrict__ h1, const float* __restrict__ as1,
    const float* __restrict__ ad1, const float* __restrict__ b1,
    const float* __restrict__ W2, float* __restrict__ h2, int N)
{
    const int lane = threadIdx.x & 63;
    const int n = blockIdx.x * (blockDim.x >> 6) + (threadIdx.x >> 6);
    if (n >= N) return;
    const int h = lane >> 3, c = lane & 7;
    const unsigned s0 = offs[n], s1 = offs[n + 1];
    const float ad = ad1[n * NHEAD + h];

    // pass A: segment max of alpha_s (8 parallel edge slots per head)
    float m = -INFINITY;
    for (unsigned j = s0 + (unsigned)c; j < s1; j += 8) {
        int s = csr[j];
        m = fmaxf(m, as1[s * NHEAD + h]);
    }
    m = fmaxf(m, __shfl_xor(m, 1));
    m = fmaxf(m, __shfl_xor(m, 2));
    m = fmaxf(m, __shfl_xor(m, 4));
    const float me = lrelu(m + ad);  // == segment max of e (lrelu monotone)

    // pass B: weighted accumulate, 4 edges in flight
    float acc = 0.f, den = 0.f;
    unsigned j = s0;
    for (; j + 4 <= s1; j += 4) {
        int sA = csr[j], sB = csr[j + 1], sC = csr[j + 2], sD = csr[j + 3];
        float aA = as1[sA * NHEAD + h], aB = as1[sB * NHEAD + h];
        float aC = as1[sC * NHEAD + h], aD = as1[sD * NHEAD + h];
        float hA = h1[(size_t)sA * NO + lane], hB = h1[(size_t)sB * NO + lane];
        float hC = h1[(size_t)sC * NO + lane], hD = h1[(size_t)sD * NO + lane];
        float pA = __expf(lrelu(aA + ad) - me);
        float pB = __expf(lrelu(aB + ad) - me);
        float pC = __expf(lrelu(aC + ad) - me);
        float pD = __expf(lrelu(aD + ad) - me);
        den += (pA + pB) + (pC + pD);
        acc = fmaf(pA, hA, acc);
        acc = fmaf(pB, hB, acc);
        acc = fmaf(pC, hC, acc);
        acc = fmaf(pD, hD, acc);
    }
    for (; j < s1; ++j) {
        int s = csr[j];
        float p = __expf(lrelu(as1[s * NHEAD + h] + ad) - me);
        den += p;
        acc = fmaf(p, h1[(size_t)s * NO + lane], acc);
    }
    float outv = fmaxf(acc / den + b1[lane], 0.f);  // +bias, ReLU

    // fused layer-2 projection: h2[n] = sum_l outv_l * W2_l
    float tt = outv * W2[lane];
    #pragma unroll
    for (int msk = 1; msk < 64; msk <<= 1) tt += __shfl_xor(tt, msk);
    if (lane == 0) h2[n] = tt;
}

// ---------------------------------------------------------------------------
// K6: layer-2 GAT (1 head, scalar). Plain per-node store, no atomics.
// ---------------------------------------------------------------------------
__global__ __launch_bounds__(256) void k_gat2(
    const unsigned* __restrict__ offs, const int* __restrict__ csr,
    const float* __restrict__ h2, const float* __restrict__ a_src2,
    const float* __restrict__ a_dst2, const float* __restrict__ b2,
    float* __restrict__ onode, int N)
{
    const int lane = threadIdx.x & 63;
    const int n = blockIdx.x * (blockDim.x >> 6) + (threadIdx.x >> 6);
    if (n >= N) return;
    const float aS = a_src2[0], aD = a_dst2[0];
    const unsigned s0 = offs[n], s1 = offs[n + 1];
    const float ad = h2[n] * aD;

    const unsigned j0 = s0 + (unsigned)lane;
    const bool has0 = (j0 < s1);
    float hs0 = 0.f;
    if (has0) hs0 = h2[csr[j0]];

    float m = has0 ? hs0 * aS : -INFINITY;
    for (unsigned j = j0 + 64; j < s1; j += 64)
        m = fmaxf(m, h2[csr[j]] * aS);
    #pragma unroll
    for (int msk = 1; msk < 64; msk <<= 1) m = fmaxf(m, __shfl_xor(m, msk));
    const float me = lrelu(m + ad);

    float num = 0.f, den = 0.f;
    if (has0) {
        float p = __expf(lrelu(hs0 * aS + ad) - me);
        num = p * hs0;
        den = p;
    }
    for (unsigned j = j0 + 64; j < s1; j += 64) {
        float hs = h2[csr[j]];
        float p = __expf(lrelu(hs * aS + ad) - me);
        num = fmaf(p, hs, num);
        den += p;
    }
    #pragma unroll
    for (int msk = 1; msk < 64; msk <<= 1) {
        num += __shfl_xor(num, msk);
        den += __shfl_xor(den, msk);
    }
    if (lane == 0) onode[n] = num / den + b2[0];
}

// ---------------------------------------------------------------------------
// K6b: mean-pool over sorted batch: one atomic pair per wave + rare boundary.
// ---------------------------------------------------------------------------
__global__ __launch_bounds__(256) void k_pool(
    const float* __restrict__ onode, const int* __restrict__ batch,
    float* __restrict__ gsum, float* __restrict__ gcnt, int N)
{
    const int lane = threadIdx.x & 63;
    const int base = (blockIdx.x * (blockDim.x >> 6) + (threadIdx.x >> 6)) * 64;
    if (base >= N) return;
    const int n = base + lane;
    const bool act = (n < N);
    float o = 0.f;
    int g = -1;
    if (act) { o = onode[n]; g = batch[n]; }
    const int g0 = __shfl(g, 0);
    const bool same = (g == g0);
    float s = (act && same) ? o : 0.f;
    float c = (act && same) ? 1.f : 0.f;
    #pragma unroll
    for (int msk = 1; msk < 64; msk <<= 1) {
        s += __shfl_xor(s, msk);
        c += __shfl_xor(c, msk);
    }
    if (lane == 0) {
        unsafeAtomicAdd(&gsum[g0], s);
        unsafeAtomicAdd(&gcnt[g0], c);
    }
    if (act && !same) {
        unsafeAtomicAdd(&gsum[g], o);
        unsafeAtomicAdd(&gcnt[g], 1.0f);
    }
}

// ---------------------------------------------------------------------------
// K7: final per-graph mean
// ---------------------------------------------------------------------------
__global__ void k_final(const float* __restrict__ gsum,
                        const float* __restrict__ gcnt,
                        float* __restrict__ out, int G)
{
    int g = blockIdx.x * blockDim.x + threadIdx.x;
    if (g < G) out[g] = gsum[g] / fmaxf(gcnt[g], 1.0f);
}

// ---------------------------------------------------------------------------
extern "C" void kernel_launch(void* const* d_in, const int* in_sizes, int n_in,
                              void* d_out, int out_size, void* d_ws, size_t ws_size,
                              hipStream_t stream)
{
    const float* x      = (const float*)d_in[0];
    const int*   eidx   = (const int*)d_in[1];
    const int*   batch  = (const int*)d_in[2];
    const float* W1     = (const float*)d_in[3];
    const float* a_src1 = (const float*)d_in[4];
    const float* a_dst1 = (const float*)d_in[5];
    const float* b1     = (const float*)d_in[6];
    const float* W2     = (const float*)d_in[7];
    const float* a_src2 = (const float*)d_in[8];
    const float* a_dst2 = (const float*)d_in[9];
    const float* b2     = (const float*)d_in[10];

    const int N = in_sizes[0] / NF;      // 50000
    const int E = in_sizes[1] / 2;       // 1600000
    const int G = out_size;              // 64
    const int ETOT = E + N;

    // workspace layout (bytes)
    char* w = (char*)d_ws;
    float*    h1     = (float*)(w + 0);            // 12,800,000
    float*    as1    = (float*)(w + 12800000);     //  1,600,000
    float*    ad1    = (float*)(w + 14400000);     //  1,600,000
    float*    h2     = (float*)(w + 16000000);     //    200,000
    unsigned* counts = (unsigned*)(w + 16200000);  //    200,000
    unsigned* offs   = (unsigned*)(w + 16400000);  //    200,064
    unsigned* cursor = (unsigned*)(w + 16600064);  //    200,000
    int*      csr    = (int*)(w + 16800064);       //  6,600,000
    float*    gsum   = (float*)(w + 23400064);     //        256
    float*    gcnt   = (float*)(w + 23400320);     //        256
    float*    onode  = (float*)(w + 23400576);     //    200,000

    hipMemsetAsync(counts, 0, (size_t)N * 4, stream);
    hipMemsetAsync(gsum, 0, 512, stream);  // gsum + gcnt

    k_gemm1<<<(N + BM - 1) / BM, 256, 0, stream>>>(x, W1, a_src1, a_dst1,
                                                   h1, as1, ad1, N);

    int eb = (ETOT + 255) / 256;
    k_hist<<<eb, 256, 0, stream>>>(eidx, E, N, counts);
    k_scan<<<1, 1024, 0, stream>>>(counts, offs, cursor, N);
    k_fill<<<eb, 256, 0, stream>>>(eidx, E, N, cursor, csr);

    k_gat1<<<(N + 3) / 4, 256, 0, stream>>>(offs, csr, h1, as1, ad1, b1, W2, h2, N);
    k_gat2<<<(N + 3) / 4, 256, 0, stream>>>(offs, csr, h2, a_src2, a_dst2, b2,
                                            onode, N);
    int pw = (N + 63) / 64;
    k_pool<<<(pw + 3) / 4, 256, 0, stream>>>(onode, batch, gsum, gcnt, N);
    k_final<<<1, 64, 0, stream>>>(gsum, gcnt, (float*)d_out, G);
}

// Round 4
// 212.490 us; speedup vs baseline: 5.4282x; 1.8759x over previous
//
#include <hip/hip_runtime.h>
#include <hip/hip_bf16.h>
#include <math.h>

#define NF 256    // input features
#define NO 64     // heads*c1 = 8*8
#define NHEAD 8
#define NEG_SLOPE 0.2f
#define BM 64     // gemm row tile
#define KB 64     // gemm k tile
#define LS 68     // gemm LDS row stride
#define BKT 128   // nodes per dst-bucket (d>>7); d_local = 7 bits
#define NBLK 256  // edge-chunk blocks for binning
#define RCAP 8192 // LDS record capacity in k_csr (mean 4237, +61 sigma margin)

__device__ __forceinline__ float lrelu(float x) { return x > 0.f ? x : NEG_SLOPE * x; }

// ---------------------------------------------------------------------------
// K1: h1 = x @ W1 (50000x256 @ 256x64) tiled GEMM + fused alpha_src/alpha_dst.
// ---------------------------------------------------------------------------
__global__ __launch_bounds__(256) void k_gemm1(
    const float* __restrict__ x, const float* __restrict__ W,
    const float* __restrict__ a_src, const float* __restrict__ a_dst,
    float* __restrict__ h1, float* __restrict__ as1, float* __restrict__ ad1,
    int N)
{
    __shared__ float xl[BM][LS];
    __shared__ float wl[KB][LS];
    const int t  = threadIdx.x;
    const int tx = t & 15;
    const int ty = t >> 4;
    const int row0 = blockIdx.x * BM;

    float acc[4][4] = {};

    for (int kc = 0; kc < NF; kc += KB) {
        #pragma unroll
        for (int i = 0; i < 4; ++i) {
            int r = (t >> 4) + 16 * i;
            int row = row0 + r; if (row >= N) row = N - 1;
            float4 v = *(const float4*)(x + (size_t)row * NF + kc + 4 * tx);
            *(float4*)&xl[r][4 * tx] = v;
        }
        #pragma unroll
        for (int i = 0; i < 4; ++i) {
            int k = (t >> 4) + 16 * i;
            float4 v = *(const float4*)(W + (size_t)(kc + k) * NO + 4 * tx);
            *(float4*)&wl[k][4 * tx] = v;
        }
        __syncthreads();

        #pragma unroll
        for (int k = 0; k < KB; k += 4) {
            float4 xv[4], wv[4];
            #pragma unroll
            for (int r = 0; r < 4; ++r)
                xv[r] = *(const float4*)&xl[4 * ty + r][k];
            #pragma unroll
            for (int kk = 0; kk < 4; ++kk)
                wv[kk] = *(const float4*)&wl[k + kk][4 * tx];
            #pragma unroll
            for (int r = 0; r < 4; ++r) {
                float4 xr = xv[r];
                #pragma unroll
                for (int kk = 0; kk < 4; ++kk) {
                    float xk = (kk == 0) ? xr.x : (kk == 1) ? xr.y : (kk == 2) ? xr.z : xr.w;
                    acc[r][0] = fmaf(xk, wv[kk].x, acc[r][0]);
                    acc[r][1] = fmaf(xk, wv[kk].y, acc[r][1]);
                    acc[r][2] = fmaf(xk, wv[kk].z, acc[r][2]);
                    acc[r][3] = fmaf(xk, wv[kk].w, acc[r][3]);
                }
            }
        }
        __syncthreads();
    }

    const float4 avs = *(const float4*)(a_src + 4 * tx);
    const float4 avd = *(const float4*)(a_dst + 4 * tx);
    #pragma unroll
    for (int r = 0; r < 4; ++r) {
        int row = row0 + 4 * ty + r;
        if (row >= N) continue;
        float4 o = make_float4(acc[r][0], acc[r][1], acc[r][2], acc[r][3]);
        *(float4*)(h1 + (size_t)row * NO + 4 * tx) = o;
        float vs = o.x * avs.x + o.y * avs.y + o.z * avs.z + o.w * avs.w;
        float vd = o.x * avd.x + o.y * avd.y + o.z * avd.z + o.w * avd.w;
        vs += __shfl_xor(vs, 1);
        vd += __shfl_xor(vd, 1);
        if ((tx & 1) == 0) {
            as1[row * NHEAD + (tx >> 1)] = vs;
            ad1[row * NHEAD + (tx >> 1)] = vd;
        }
    }
}

// ---------------------------------------------------------------------------
// B1: per-chunk-block bucket histogram (LDS atomics) -> M[b][blk], totals T[b]
// ---------------------------------------------------------------------------
__global__ __launch_bounds__(256) void k_bhist(
    const int* __restrict__ eidx, int E, int N, int NB, int CH,
    unsigned* __restrict__ M, unsigned* __restrict__ T)
{
    __shared__ unsigned hist[512];
    for (int i = threadIdx.x; i < NB; i += 256) hist[i] = 0;
    __syncthreads();
    const int blk = blockIdx.x;
    const int lo = blk * CH;
    const int hi = min(lo + CH, E + N);
    for (int i = lo + (int)threadIdx.x; i < hi; i += 256) {
        int d = (i < E) ? eidx[E + i] : (i - E);
        atomicAdd(&hist[d >> 7], 1u);
    }
    __syncthreads();
    for (int b = threadIdx.x; b < NB; b += 256) {
        unsigned c = hist[b];
        M[(size_t)b * NBLK + blk] = c;
        if (c) atomicAdd(&T[b], c);
    }
}

// ---------------------------------------------------------------------------
// B2: exclusive scan of bucket totals T -> Bbase[0..NB]  (single block)
// ---------------------------------------------------------------------------
__global__ __launch_bounds__(512) void k_btot(
    const unsigned* __restrict__ T, unsigned* __restrict__ Bbase, int NB)
{
    __shared__ unsigned ws[8];
    const int t = threadIdx.x, lane = t & 63, w = t >> 6;
    unsigned v = (t < NB) ? T[t] : 0u;
    unsigned p = v;
    #pragma unroll
    for (int d = 1; d < 64; d <<= 1) {
        unsigned q = __shfl_up(p, d);
        if (lane >= d) p += q;
    }
    if (lane == 63) ws[w] = p;
    __syncthreads();
    unsigned wb = 0;
    for (int j = 0; j < w; ++j) wb += ws[j];
    if (t <= NB) Bbase[t] = wb + p - v;   // exclusive prefix; t==NB gets total
}

// ---------------------------------------------------------------------------
// B3: per-bucket exclusive scan of M row (+ bucket base) -> scatter cursors
// ---------------------------------------------------------------------------
__global__ __launch_bounds__(256) void k_bscan3(
    unsigned* __restrict__ M, const unsigned* __restrict__ Bbase, int NB)
{
    __shared__ unsigned ws[4];
    const int b = blockIdx.x;
    const int lane = threadIdx.x & 63, w = threadIdx.x >> 6;
    unsigned v = M[(size_t)b * NBLK + threadIdx.x];
    unsigned p = v;
    #pragma unroll
    for (int d = 1; d < 64; d <<= 1) {
        unsigned q = __shfl_up(p, d);
        if (lane >= d) p += q;
    }
    if (lane == 63) ws[w] = p;
    __syncthreads();
    unsigned wb = 0;
    for (int j = 0; j < w; ++j) wb += ws[j];
    M[(size_t)b * NBLK + threadIdx.x] = Bbase[b] + wb + p - v;
}

// ---------------------------------------------------------------------------
// B4: scatter packed records (s<<7 | d_local) into bucket-contiguous regions.
// Each (block,bucket) slice is block-private and sequential -> ~no write amp.
// ---------------------------------------------------------------------------
__global__ __launch_bounds__(256) void k_bscatter(
    const int* __restrict__ eidx, int E, int N, int NB, int CH,
    const unsigned* __restrict__ M, unsigned* __restrict__ rbuf)
{
    __shared__ unsigned cur[512];
    const int blk = blockIdx.x;
    for (int b = threadIdx.x; b < NB; b += 256)
        cur[b] = M[(size_t)b * NBLK + blk];
    __syncthreads();
    const int lo = blk * CH;
    const int hi = min(lo + CH, E + N);
    for (int i = lo + (int)threadIdx.x; i < hi; i += 256) {
        int s, d;
        if (i < E) { s = eidx[i]; d = eidx[E + i]; }
        else       { s = i - E;   d = i - E; }
        unsigned pos = atomicAdd(&cur[d >> 7], 1u);
        rbuf[pos] = ((unsigned)s << 7) | (unsigned)(d & (BKT - 1));
    }
}

// ---------------------------------------------------------------------------
// B5: per-bucket LDS counting sort -> node-ordered csr (IN PLACE over rbuf,
// block-private window, read-all-then-write) + node-level offs.
// ---------------------------------------------------------------------------
__global__ __launch_bounds__(256) void k_csr(
    const unsigned* __restrict__ Bbase, int N, int NB,
    unsigned* __restrict__ rbuf, unsigned* __restrict__ offs)
{
    __shared__ unsigned recs[RCAP];
    __shared__ unsigned nhist[BKT];
    __shared__ unsigned ncur[BKT];
    __shared__ unsigned wtotS;
    const int b = blockIdx.x;
    const unsigned base = Bbase[b], end = Bbase[b + 1];
    const int cnt = (int)(end - base);
    const int nodes = min(BKT, N - b * BKT);

    for (int i = threadIdx.x; i < BKT; i += 256) nhist[i] = 0;
    __syncthreads();
    // phase 1: stage records + node histogram (cnt <= RCAP for this dataset)
    for (int i = threadIdx.x; i < cnt; i += 256) {
        unsigned r = rbuf[base + i];
        recs[i] = r;
        atomicAdd(&nhist[r & (BKT - 1)], 1u);
    }
    __syncthreads();
    // phase 2: exclusive scan of 128 node counts (threads duplicated 2x)
    const int tl = threadIdx.x & 127;
    unsigned v = nhist[tl], p = v;
    #pragma unroll
    for (int d = 1; d < 64; d <<= 1) {
        unsigned q = __shfl_up(p, d);
        if ((tl & 63) >= d) p += q;
    }
    if (threadIdx.x == 63) wtotS = p;
    __syncthreads();
    unsigned excl = base + ((tl >= 64) ? wtotS : 0u) + p - v;
    if (threadIdx.x < 128) {
        ncur[tl] = excl;
        if (tl < nodes) offs[b * BKT + tl] = excl;
    }
    if (b == NB - 1 && threadIdx.x == 0) offs[N] = end;
    __syncthreads();
    // phase 3: scatter s into node-sorted position (writes stay in L2 window)
    for (int i = threadIdx.x; i < cnt; i += 256) {
        unsigned r = recs[i];
        unsigned pos = atomicAdd(&ncur[r & (BKT - 1)], 1u);
        rbuf[pos] = r >> 7;
    }
}

// ---------------------------------------------------------------------------
// K5: layer-1 GAT aggregation, one wave per dst node, pass-B x4 unrolled.
// Epilogue: out = relu(acc/denom + b1); h2[n] = out . W2 (wave reduce).
// ---------------------------------------------------------------------------
__global__ __launch_bounds__(256) void k_gat1(
    const unsigned* __restrict__ offs, const int* __restrict__ csr,
    const float* __restrict__ h1, const float* __restrict__ as1,
    const float* __restrict__ ad1, const float* __restrict__ b1,
    const float* __restrict__ W2, float* __restrict__ h2, int N)
{
    const int lane = threadIdx.x & 63;
    const int n = blockIdx.x * (blockDim.x >> 6) + (threadIdx.x >> 6);
    if (n >= N) return;
    const int h = lane >> 3, c = lane & 7;
    const unsigned s0 = offs[n], s1 = offs[n + 1];
    const float ad = ad1[n * NHEAD + h];

    float m = -INFINITY;
    for (unsigned j = s0 + (unsigned)c; j < s1; j += 8) {
        int s = csr[j];
        m = fmaxf(m, as1[s * NHEAD + h]);
    }
    m = fmaxf(m, __shfl_xor(m, 1));
    m = fmaxf(m, __shfl_xor(m, 2));
    m = fmaxf(m, __shfl_xor(m, 4));
    const float me = lrelu(m + ad);

    float acc = 0.f, den = 0.f;
    unsigned j = s0;
    for (; j + 4 <= s1; j += 4) {
        int sA = csr[j], sB = csr[j + 1], sC = csr[j + 2], sD = csr[j + 3];
        float aA = as1[sA * NHEAD + h], aB = as1[sB * NHEAD + h];
        float aC = as1[sC * NHEAD + h], aD = as1[sD * NHEAD + h];
        float hA = h1[(size_t)sA * NO + lane], hB = h1[(size_t)sB * NO + lane];
        float hC = h1[(size_t)sC * NO + lane], hD = h1[(size_t)sD * NO + lane];
        float pA = __expf(lrelu(aA + ad) - me);
        float pB = __expf(lrelu(aB + ad) - me);
        float pC = __expf(lrelu(aC + ad) - me);
        float pD = __expf(lrelu(aD + ad) - me);
        den += (pA + pB) + (pC + pD);
        acc = fmaf(pA, hA, acc);
        acc = fmaf(pB, hB, acc);
        acc = fmaf(pC, hC, acc);
        acc = fmaf(pD, hD, acc);
    }
    for (; j < s1; ++j) {
        int s = csr[j];
        float p = __expf(lrelu(as1[s * NHEAD + h] + ad) - me);
        den += p;
        acc = fmaf(p, h1[(size_t)s * NO + lane], acc);
    }
    float outv = fmaxf(acc / den + b1[lane], 0.f);

    float tt = outv * W2[lane];
    #pragma unroll
    for (int msk = 1; msk < 64; msk <<= 1) tt += __shfl_xor(tt, msk);
    if (lane == 0) h2[n] = tt;
}

// ---------------------------------------------------------------------------
// K6: layer-2 GAT (1 head, scalar). Plain per-node store.
// ---------------------------------------------------------------------------
__global__ __launch_bounds__(256) void k_gat2(
    const unsigned* __restrict__ offs, const int* __restrict__ csr,
    const float* __restrict__ h2, const float* __restrict__ a_src2,
    const float* __restrict__ a_dst2, const float* __restrict__ b2,
    float* __restrict__ onode, int N)
{
    const int lane = threadIdx.x & 63;
    const int n = blockIdx.x * (blockDim.x >> 6) + (threadIdx.x >> 6);
    if (n >= N) return;
    const float aS = a_src2[0], aD = a_dst2[0];
    const unsigned s0 = offs[n], s1 = offs[n + 1];
    const float ad = h2[n] * aD;

    const unsigned j0 = s0 + (unsigned)lane;
    const bool has0 = (j0 < s1);
    float hs0 = 0.f;
    if (has0) hs0 = h2[csr[j0]];

    float m = has0 ? hs0 * aS : -INFINITY;
    for (unsigned j = j0 + 64; j < s1; j += 64)
        m = fmaxf(m, h2[csr[j]] * aS);
    #pragma unroll
    for (int msk = 1; msk < 64; msk <<= 1) m = fmaxf(m, __shfl_xor(m, msk));
    const float me = lrelu(m + ad);

    float num = 0.f, den = 0.f;
    if (has0) {
        float p = __expf(lrelu(hs0 * aS + ad) - me);
        num = p * hs0;
        den = p;
    }
    for (unsigned j = j0 + 64; j < s1; j += 64) {
        float hs = h2[csr[j]];
        float p = __expf(lrelu(hs * aS + ad) - me);
        num = fmaf(p, hs, num);
        den += p;
    }
    #pragma unroll
    for (int msk = 1; msk < 64; msk <<= 1) {
        num += __shfl_xor(num, msk);
        den += __shfl_xor(den, msk);
    }
    if (lane == 0) onode[n] = num / den + b2[0];
}

// ---------------------------------------------------------------------------
// K6b: mean-pool over sorted batch: one atomic pair per wave + rare boundary.
// ---------------------------------------------------------------------------
__global__ __launch_bounds__(256) void k_pool(
    const float* __restrict__ onode, const int* __restrict__ batch,
    float* __restrict__ gsum, float* __restrict__ gcnt, int N)
{
    const int lane = threadIdx.x & 63;
    const int base = (blockIdx.x * (blockDim.x >> 6) + (threadIdx.x >> 6)) * 64;
    if (base >= N) return;
    const int n = base + lane;
    const bool act = (n < N);
    float o = 0.f;
    int g = -1;
    if (act) { o = onode[n]; g = batch[n]; }
    const int g0 = __shfl(g, 0);
    const bool same = (g == g0);
    float s = (act && same) ? o : 0.f;
    float c = (act && same) ? 1.f : 0.f;
    #pragma unroll
    for (int msk = 1; msk < 64; msk <<= 1) {
        s += __shfl_xor(s, msk);
        c += __shfl_xor(c, msk);
    }
    if (lane == 0) {
        unsafeAtomicAdd(&gsum[g0], s);
        unsafeAtomicAdd(&gcnt[g0], c);
    }
    if (act && !same) {
        unsafeAtomicAdd(&gsum[g], o);
        unsafeAtomicAdd(&gcnt[g], 1.0f);
    }
}

// ---------------------------------------------------------------------------
// K7: final per-graph mean
// ---------------------------------------------------------------------------
__global__ void k_final(const float* __restrict__ gsum,
                        const float* __restrict__ gcnt,
                        float* __restrict__ out, int G)
{
    int g = blockIdx.x * blockDim.x + threadIdx.x;
    if (g < G) out[g] = gsum[g] / fmaxf(gcnt[g], 1.0f);
}

// ---------------------------------------------------------------------------
extern "C" void kernel_launch(void* const* d_in, const int* in_sizes, int n_in,
                              void* d_out, int out_size, void* d_ws, size_t ws_size,
                              hipStream_t stream)
{
    const float* x      = (const float*)d_in[0];
    const int*   eidx   = (const int*)d_in[1];
    const int*   batch  = (const int*)d_in[2];
    const float* W1     = (const float*)d_in[3];
    const float* a_src1 = (const float*)d_in[4];
    const float* a_dst1 = (const float*)d_in[5];
    const float* b1     = (const float*)d_in[6];
    const float* W2     = (const float*)d_in[7];
    const float* a_src2 = (const float*)d_in[8];
    const float* a_dst2 = (const float*)d_in[9];
    const float* b2     = (const float*)d_in[10];

    const int N = in_sizes[0] / NF;      // 50000
    const int E = in_sizes[1] / 2;       // 1600000
    const int G = out_size;              // 64
    const int ETOT = E + N;
    const int NB = (N + BKT - 1) / BKT;  // 391 buckets (<=512)
    const int CH = (ETOT + NBLK - 1) / NBLK;

    // workspace layout (bytes), ~23.6MB (same footprint as prior rounds)
    char* w = (char*)d_ws;
    float*    h1    = (float*)(w + 0);            // 12,800,000
    float*    as1   = (float*)(w + 12800000);     //  1,600,000
    float*    ad1   = (float*)(w + 14400000);     //  1,600,000
    float*    h2    = (float*)(w + 16000000);     //    200,000
    unsigned* offs  = (unsigned*)(w + 16200000);  //    200,064
    unsigned* rbuf  = (unsigned*)(w + 16400064);  //  6,600,000 (records -> csr in place)
    unsigned* M     = (unsigned*)(w + 23000064);  //    400,384 (NB*NBLK)
    unsigned* T     = (unsigned*)(w + 23400448);  //      2,048
    unsigned* Bbase = (unsigned*)(w + 23402496);  //      2,048
    float*    gsum  = (float*)(w + 23404544);     //        256
    float*    gcnt  = (float*)(w + 23404800);     //        256
    float*    onode = (float*)(w + 23405056);     //    200,000

    hipMemsetAsync(T, 0, (size_t)(NB + 1) * 4, stream);
    hipMemsetAsync(gsum, 0, 512, stream);  // gsum + gcnt

    k_gemm1<<<(N + BM - 1) / BM, 256, 0, stream>>>(x, W1, a_src1, a_dst1,
                                                   h1, as1, ad1, N);

    k_bhist<<<NBLK, 256, 0, stream>>>(eidx, E, N, NB, CH, M, T);
    k_btot<<<1, 512, 0, stream>>>(T, Bbase, NB);
    k_bscan3<<<NB, 256, 0, stream>>>(M, Bbase, NB);
    k_bscatter<<<NBLK, 256, 0, stream>>>(eidx, E, N, NB, CH, M, rbuf);
    k_csr<<<NB, 256, 0, stream>>>(Bbase, N, NB, rbuf, offs);

    const int* csr = (const int*)rbuf;
    k_gat1<<<(N + 3) / 4, 256, 0, stream>>>(offs, csr, h1, as1, ad1, b1, W2, h2, N);
    k_gat2<<<(N + 3) / 4, 256, 0, stream>>>(offs, csr, h2, a_src2, a_dst2, b2,
                                            onode, N);
    int pw = (N + 63) / 64;
    k_pool<<<(pw + 3) / 4, 256, 0, stream>>>(onode, batch, gsum, gcnt, N);
    k_final<<<1, 64, 0, stream>>>(gsum, gcnt, (float*)d_out, G);
}

// Round 5
// 181.768 us; speedup vs baseline: 6.3457x; 1.1690x over previous
//
#include <hip/hip_runtime.h>
#include <hip/hip_bf16.h>
#include <hip/hip_fp16.h>
#include <math.h>

#define NF 256    // input features
#define NO 64     // heads*c1 = 8*8
#define NHEAD 8
#define NEG_SLOPE 0.2f
#define BM 64     // gemm row tile
#define KB 64     // gemm k tile
#define LS 68     // gemm LDS row stride
#define BKT 128   // nodes per dst-bucket (d>>7); d_local = 7 bits
#define NBLK 256  // edge-chunk blocks for binning
#define RCAP 8192 // LDS record capacity in k_csr

__device__ __forceinline__ float lrelu(float x) { return x > 0.f ? x : NEG_SLOPE * x; }

// ---------------------------------------------------------------------------
// K1: h1 = x @ W1 (50000x256 @ 256x64) tiled GEMM + fused alpha_src/alpha_dst.
// h1 stored as fp16 (halves gather bytes downstream); alphas stay f32.
// ---------------------------------------------------------------------------
__global__ __launch_bounds__(256) void k_gemm1(
    const float* __restrict__ x, const float* __restrict__ W,
    const float* __restrict__ a_src, const float* __restrict__ a_dst,
    __half* __restrict__ h1h, float* __restrict__ as1, float* __restrict__ ad1,
    int N)
{
    __shared__ float xl[BM][LS];
    __shared__ float wl[KB][LS];
    const int t  = threadIdx.x;
    const int tx = t & 15;
    const int ty = t >> 4;
    const int row0 = blockIdx.x * BM;

    float acc[4][4] = {};

    for (int kc = 0; kc < NF; kc += KB) {
        #pragma unroll
        for (int i = 0; i < 4; ++i) {
            int r = (t >> 4) + 16 * i;
            int row = row0 + r; if (row >= N) row = N - 1;
            float4 v = *(const float4*)(x + (size_t)row * NF + kc + 4 * tx);
            *(float4*)&xl[r][4 * tx] = v;
        }
        #pragma unroll
        for (int i = 0; i < 4; ++i) {
            int k = (t >> 4) + 16 * i;
            float4 v = *(const float4*)(W + (size_t)(kc + k) * NO + 4 * tx);
            *(float4*)&wl[k][4 * tx] = v;
        }
        __syncthreads();

        #pragma unroll
        for (int k = 0; k < KB; k += 4) {
            float4 xv[4], wv[4];
            #pragma unroll
            for (int r = 0; r < 4; ++r)
                xv[r] = *(const float4*)&xl[4 * ty + r][k];
            #pragma unroll
            for (int kk = 0; kk < 4; ++kk)
                wv[kk] = *(const float4*)&wl[k + kk][4 * tx];
            #pragma unroll
            for (int r = 0; r < 4; ++r) {
                float4 xr = xv[r];
                #pragma unroll
                for (int kk = 0; kk < 4; ++kk) {
                    float xk = (kk == 0) ? xr.x : (kk == 1) ? xr.y : (kk == 2) ? xr.z : xr.w;
                    acc[r][0] = fmaf(xk, wv[kk].x, acc[r][0]);
                    acc[r][1] = fmaf(xk, wv[kk].y, acc[r][1]);
                    acc[r][2] = fmaf(xk, wv[kk].z, acc[r][2]);
                    acc[r][3] = fmaf(xk, wv[kk].w, acc[r][3]);
                }
            }
        }
        __syncthreads();
    }

    const float4 avs = *(const float4*)(a_src + 4 * tx);
    const float4 avd = *(const float4*)(a_dst + 4 * tx);
    #pragma unroll
    for (int r = 0; r < 4; ++r) {
        int row = row0 + 4 * ty + r;
        if (row >= N) continue;
        float4 o = make_float4(acc[r][0], acc[r][1], acc[r][2], acc[r][3]);
        __half2 p0 = __float22half2_rn(make_float2(o.x, o.y));
        __half2 p1 = __float22half2_rn(make_float2(o.z, o.w));
        __half2* dst2 = (__half2*)(h1h + (size_t)row * NO + 4 * tx);
        dst2[0] = p0;
        dst2[1] = p1;
        float vs = o.x * avs.x + o.y * avs.y + o.z * avs.z + o.w * avs.w;
        float vd = o.x * avd.x + o.y * avd.y + o.z * avd.z + o.w * avd.w;
        vs += __shfl_xor(vs, 1);
        vd += __shfl_xor(vd, 1);
        if ((tx & 1) == 0) {
            as1[row * NHEAD + (tx >> 1)] = vs;
            ad1[row * NHEAD + (tx >> 1)] = vd;
        }
    }
}

// ---------------------------------------------------------------------------
// B1: per-chunk-block bucket histogram (LDS atomics) -> M[b][blk], totals T[b]
// ---------------------------------------------------------------------------
__global__ __launch_bounds__(256) void k_bhist(
    const int* __restrict__ eidx, int E, int N, int NB, int CH,
    unsigned* __restrict__ M, unsigned* __restrict__ T)
{
    __shared__ unsigned hist[512];
    for (int i = threadIdx.x; i < NB; i += 256) hist[i] = 0;
    __syncthreads();
    const int blk = blockIdx.x;
    const int lo = blk * CH;
    const int hi = min(lo + CH, E + N);
    for (int i = lo + (int)threadIdx.x; i < hi; i += 256) {
        int d = (i < E) ? eidx[E + i] : (i - E);
        atomicAdd(&hist[d >> 7], 1u);
    }
    __syncthreads();
    for (int b = threadIdx.x; b < NB; b += 256) {
        unsigned c = hist[b];
        M[(size_t)b * NBLK + blk] = c;
        if (c) atomicAdd(&T[b], c);
    }
}

// ---------------------------------------------------------------------------
// B2: exclusive scan of bucket totals T -> Bbase[0..NB]  (single block)
// ---------------------------------------------------------------------------
__global__ __launch_bounds__(512) void k_btot(
    const unsigned* __restrict__ T, unsigned* __restrict__ Bbase, int NB)
{
    __shared__ unsigned ws[8];
    const int t = threadIdx.x, lane = t & 63, w = t >> 6;
    unsigned v = (t < NB) ? T[t] : 0u;
    unsigned p = v;
    #pragma unroll
    for (int d = 1; d < 64; d <<= 1) {
        unsigned q = __shfl_up(p, d);
        if (lane >= d) p += q;
    }
    if (lane == 63) ws[w] = p;
    __syncthreads();
    unsigned wb = 0;
    for (int j = 0; j < w; ++j) wb += ws[j];
    if (t <= NB) Bbase[t] = wb + p - v;
}

// ---------------------------------------------------------------------------
// B3: per-bucket exclusive scan of M row (+ bucket base) -> scatter cursors
// ---------------------------------------------------------------------------
__global__ __launch_bounds__(256) void k_bscan3(
    unsigned* __restrict__ M, const unsigned* __restrict__ Bbase, int NB)
{
    __shared__ unsigned ws[4];
    const int b = blockIdx.x;
    const int lane = threadIdx.x & 63, w = threadIdx.x >> 6;
    unsigned v = M[(size_t)b * NBLK + threadIdx.x];
    unsigned p = v;
    #pragma unroll
    for (int d = 1; d < 64; d <<= 1) {
        unsigned q = __shfl_up(p, d);
        if (lane >= d) p += q;
    }
    if (lane == 63) ws[w] = p;
    __syncthreads();
    unsigned wb = 0;
    for (int j = 0; j < w; ++j) wb += ws[j];
    M[(size_t)b * NBLK + threadIdx.x] = Bbase[b] + wb + p - v;
}

// ---------------------------------------------------------------------------
// B4: scatter packed records (s<<7 | d_local) into bucket-contiguous regions.
// ---------------------------------------------------------------------------
__global__ __launch_bounds__(256) void k_bscatter(
    const int* __restrict__ eidx, int E, int N, int NB, int CH,
    const unsigned* __restrict__ M, unsigned* __restrict__ rbuf)
{
    __shared__ unsigned cur[512];
    const int blk = blockIdx.x;
    for (int b = threadIdx.x; b < NB; b += 256)
        cur[b] = M[(size_t)b * NBLK + blk];
    __syncthreads();
    const int lo = blk * CH;
    const int hi = min(lo + CH, E + N);
    for (int i = lo + (int)threadIdx.x; i < hi; i += 256) {
        int s, d;
        if (i < E) { s = eidx[i]; d = eidx[E + i]; }
        else       { s = i - E;   d = i - E; }
        unsigned pos = atomicAdd(&cur[d >> 7], 1u);
        rbuf[pos] = ((unsigned)s << 7) | (unsigned)(d & (BKT - 1));
    }
}

// ---------------------------------------------------------------------------
// B5: per-bucket LDS counting sort -> node-ordered csr (in place) + offs.
// ---------------------------------------------------------------------------
__global__ __launch_bounds__(256) void k_csr(
    const unsigned* __restrict__ Bbase, int N, int NB,
    unsigned* __restrict__ rbuf, unsigned* __restrict__ offs)
{
    __shared__ unsigned recs[RCAP];
    __shared__ unsigned nhist[BKT];
    __shared__ unsigned ncur[BKT];
    __shared__ unsigned wtotS;
    const int b = blockIdx.x;
    const unsigned base = Bbase[b], end = Bbase[b + 1];
    const int cnt = (int)(end - base);
    const int nodes = min(BKT, N - b * BKT);

    for (int i = threadIdx.x; i < BKT; i += 256) nhist[i] = 0;
    __syncthreads();
    for (int i = threadIdx.x; i < cnt; i += 256) {
        unsigned r = rbuf[base + i];
        recs[i] = r;
        atomicAdd(&nhist[r & (BKT - 1)], 1u);
    }
    __syncthreads();
    const int tl = threadIdx.x & 127;
    unsigned v = nhist[tl], p = v;
    #pragma unroll
    for (int d = 1; d < 64; d <<= 1) {
        unsigned q = __shfl_up(p, d);
        if ((tl & 63) >= d) p += q;
    }
    if (threadIdx.x == 63) wtotS = p;
    __syncthreads();
    unsigned excl = base + ((tl >= 64) ? wtotS : 0u) + p - v;
    if (threadIdx.x < 128) {
        ncur[tl] = excl;
        if (tl < nodes) offs[b * BKT + tl] = excl;
    }
    if (b == NB - 1 && threadIdx.x == 0) offs[N] = end;
    __syncthreads();
    for (int i = threadIdx.x; i < cnt; i += 256) {
        unsigned r = recs[i];
        unsigned pos = atomicAdd(&ncur[r & (BKT - 1)], 1u);
        rbuf[pos] = r >> 7;
    }
}

// ---------------------------------------------------------------------------
// K5: layer-1 GAT aggregation. One wave per dst node; HALF-WAVE per edge:
// lanes 0-31 process even edge slots, 32-63 odd; each lane holds 2 channels
// (half2). No segment-max pass: alpha = exp(e)/sum(exp(e)) is shift-invariant
// and |e| <= ~4 here, so f32 exp is exact-safe without it.
// Epilogue: combine halves, out = relu(acc/den + b1), h2 = out.W2.
// ---------------------------------------------------------------------------
__global__ __launch_bounds__(256) void k_gat1(
    const unsigned* __restrict__ offs, const int* __restrict__ csr,
    const __half2* __restrict__ h1p, const float* __restrict__ as1,
    const float* __restrict__ ad1, const float* __restrict__ b1,
    const float* __restrict__ W2, float* __restrict__ h2, int N)
{
    const int lane = threadIdx.x & 63;
    const int n = blockIdx.x * (blockDim.x >> 6) + (threadIdx.x >> 6);
    if (n >= N) return;
    const int l2 = lane & 31;        // channel pair index (ch = 2*l2, 2*l2+1)
    const int hw = lane >> 5;        // half-wave: which edge-slot parity
    const int h  = l2 >> 2;          // head = ch>>3 = (2*l2)>>3
    const unsigned s0 = offs[n];
    const unsigned deg = offs[n + 1] - s0;
    const float ad = ad1[n * NHEAD + h];

    float accx = 0.f, accy = 0.f, den = 0.f;
    unsigned k = (unsigned)hw;
    // 4 edges per wave iteration (2 per half) -> 2 gathers in flight per lane
    for (; k + 2 < deg; k += 4) {
        int sA = csr[s0 + k], sB = csr[s0 + k + 2];
        float aA = as1[sA * NHEAD + h], aB = as1[sB * NHEAD + h];
        __half2 hA = h1p[(size_t)sA * 32 + l2];
        __half2 hB = h1p[(size_t)sB * 32 + l2];
        float pA = __expf(lrelu(aA + ad));
        float pB = __expf(lrelu(aB + ad));
        float2 fA = __half22float2(hA), fB = __half22float2(hB);
        den += pA + pB;
        accx = fmaf(pA, fA.x, accx); accy = fmaf(pA, fA.y, accy);
        accx = fmaf(pB, fB.x, accx); accy = fmaf(pB, fB.y, accy);
    }
    for (; k < deg; k += 2) {
        int s = csr[s0 + k];
        float a = as1[s * NHEAD + h];
        __half2 hv = h1p[(size_t)s * 32 + l2];
        float p = __expf(lrelu(a + ad));
        float2 f = __half22float2(hv);
        den += p;
        accx = fmaf(p, f.x, accx); accy = fmaf(p, f.y, accy);
    }
    // combine the two halves (same channels live in lane and lane^32)
    accx += __shfl_xor(accx, 32);
    accy += __shfl_xor(accy, 32);
    den  += __shfl_xor(den, 32);

    const float2 bb = ((const float2*)b1)[l2];
    const float2 w2 = ((const float2*)W2)[l2];
    float inv = 1.f / den;
    float ox = fmaxf(fmaf(accx, inv, bb.x), 0.f);
    float oy = fmaxf(fmaf(accy, inv, bb.y), 0.f);
    float tt = ox * w2.x + oy * w2.y;
    #pragma unroll
    for (int msk = 1; msk < 32; msk <<= 1) tt += __shfl_xor(tt, msk);
    if (lane == 0) h2[n] = tt;
}

// ---------------------------------------------------------------------------
// K6: layer-2 GAT (1 head, scalar). No max pass (|e| <= ~15, f32-safe;
// softmax is shift-invariant). Single gather loop.
// ---------------------------------------------------------------------------
__global__ __launch_bounds__(256) void k_gat2(
    const unsigned* __restrict__ offs, const int* __restrict__ csr,
    const float* __restrict__ h2, const float* __restrict__ a_src2,
    const float* __restrict__ a_dst2, const float* __restrict__ b2,
    float* __restrict__ onode, int N)
{
    const int lane = threadIdx.x & 63;
    const int n = blockIdx.x * (blockDim.x >> 6) + (threadIdx.x >> 6);
    if (n >= N) return;
    const float aS = a_src2[0], aD = a_dst2[0];
    const unsigned s0 = offs[n], s1 = offs[n + 1];
    const float ad = h2[n] * aD;

    float num = 0.f, den = 0.f;
    for (unsigned j = s0 + (unsigned)lane; j < s1; j += 64) {
        float hs = h2[csr[j]];
        float p = __expf(lrelu(hs * aS + ad));
        num = fmaf(p, hs, num);
        den += p;
    }
    #pragma unroll
    for (int msk = 1; msk < 64; msk <<= 1) {
        num += __shfl_xor(num, msk);
        den += __shfl_xor(den, msk);
    }
    if (lane == 0) onode[n] = num / den + b2[0];
}

// ---------------------------------------------------------------------------
// K6b: mean-pool over sorted batch: one atomic pair per wave + rare boundary.
// ---------------------------------------------------------------------------
__global__ __launch_bounds__(256) void k_pool(
    const float* __restrict__ onode, const int* __restrict__ batch,
    float* __restrict__ gsum, float* __restrict__ gcnt, int N)
{
    const int lane = threadIdx.x & 63;
    const int base = (blockIdx.x * (blockDim.x >> 6) + (threadIdx.x >> 6)) * 64;
    if (base >= N) return;
    const int n = base + lane;
    const bool act = (n < N);
    float o = 0.f;
    int g = -1;
    if (act) { o = onode[n]; g = batch[n]; }
    const int g0 = __shfl(g, 0);
    const bool same = (g == g0);
    float s = (act && same) ? o : 0.f;
    float c = (act && same) ? 1.f : 0.f;
    #pragma unroll
    for (int msk = 1; msk < 64; msk <<= 1) {
        s += __shfl_xor(s, msk);
        c += __shfl_xor(c, msk);
    }
    if (lane == 0) {
        unsafeAtomicAdd(&gsum[g0], s);
        unsafeAtomicAdd(&gcnt[g0], c);
    }
    if (act && !same) {
        unsafeAtomicAdd(&gsum[g], o);
        unsafeAtomicAdd(&gcnt[g], 1.0f);
    }
}

// ---------------------------------------------------------------------------
// K7: final per-graph mean
// ---------------------------------------------------------------------------
__global__ void k_final(const float* __restrict__ gsum,
                        const float* __restrict__ gcnt,
                        float* __restrict__ out, int G)
{
    int g = blockIdx.x * blockDim.x + threadIdx.x;
    if (g < G) out[g] = gsum[g] / fmaxf(gcnt[g], 1.0f);
}

// ---------------------------------------------------------------------------
extern "C" void kernel_launch(void* const* d_in, const int* in_sizes, int n_in,
                              void* d_out, int out_size, void* d_ws, size_t ws_size,
                              hipStream_t stream)
{
    const float* x      = (const float*)d_in[0];
    const int*   eidx   = (const int*)d_in[1];
    const int*   batch  = (const int*)d_in[2];
    const float* W1     = (const float*)d_in[3];
    const float* a_src1 = (const float*)d_in[4];
    const float* a_dst1 = (const float*)d_in[5];
    const float* b1     = (const float*)d_in[6];
    const float* W2     = (const float*)d_in[7];
    const float* a_src2 = (const float*)d_in[8];
    const float* a_dst2 = (const float*)d_in[9];
    const float* b2     = (const float*)d_in[10];

    const int N = in_sizes[0] / NF;      // 50000
    const int E = in_sizes[1] / 2;       // 1600000
    const int G = out_size;              // 64
    const int ETOT = E + N;
    const int NB = (N + BKT - 1) / BKT;  // 391 buckets
    const int CH = (ETOT + NBLK - 1) / NBLK;

    // workspace layout (bytes)
    char* w = (char*)d_ws;
    __half*   h1h   = (__half*)(w + 0);           //  6,400,000 (fp16)
    float*    as1   = (float*)(w + 6400000);      //  1,600,000
    float*    ad1   = (float*)(w + 8000000);      //  1,600,000
    float*    h2    = (float*)(w + 9600000);      //    200,000
    unsigned* offs  = (unsigned*)(w + 9800000);   //    200,064
    unsigned* rbuf  = (unsigned*)(w + 10000064);  //  6,600,000 (records -> csr)
    unsigned* M     = (unsigned*)(w + 16600064);  //    400,384
    unsigned* T     = (unsigned*)(w + 17000448);  //      2,048
    unsigned* Bbase = (unsigned*)(w + 17002496);  //      2,048
    float*    gsum  = (float*)(w + 17004544);     //        256
    float*    gcnt  = (float*)(w + 17004800);     //        256
    float*    onode = (float*)(w + 17005056);     //    200,000

    hipMemsetAsync(T, 0, (size_t)(NB + 1) * 4, stream);
    hipMemsetAsync(gsum, 0, 512, stream);  // gsum + gcnt

    k_gemm1<<<(N + BM - 1) / BM, 256, 0, stream>>>(x, W1, a_src1, a_dst1,
                                                   h1h, as1, ad1, N);

    k_bhist<<<NBLK, 256, 0, stream>>>(eidx, E, N, NB, CH, M, T);
    k_btot<<<1, 512, 0, stream>>>(T, Bbase, NB);
    k_bscan3<<<NB, 256, 0, stream>>>(M, Bbase, NB);
    k_bscatter<<<NBLK, 256, 0, stream>>>(eidx, E, N, NB, CH, M, rbuf);
    k_csr<<<NB, 256, 0, stream>>>(Bbase, N, NB, rbuf, offs);

    const int* csr = (const int*)rbuf;
    k_gat1<<<(N + 3) / 4, 256, 0, stream>>>(offs, csr, (const __half2*)h1h,
                                            as1, ad1, b1, W2, h2, N);
    k_gat2<<<(N + 3) / 4, 256, 0, stream>>>(offs, csr, h2, a_src2, a_dst2, b2,
                                            onode, N);
    int pw = (N + 63) / 64;
    k_pool<<<(pw + 3) / 4, 256, 0, stream>>>(onode, batch, gsum, gcnt, N);
    k_final<<<1, 64, 0, stream>>>(gsum, gcnt, (float*)d_out, G);
}

// Round 6
// 155.042 us; speedup vs baseline: 7.4396x; 1.1724x over previous
//
#include <hip/hip_runtime.h>
#include <hip/hip_bf16.h>
#include <hip/hip_fp16.h>
#include <math.h>

#define NF 256    // input features
#define NO 64     // heads*c1 = 8*8
#define NHEAD 8
#define NEG_SLOPE 0.2f
#define BM 64     // gemm row tile
#define KB 64     // gemm k tile
#define LS 68     // gemm LDS row stride
#define BKT 128   // nodes per dst-bucket (d>>7); d_local = 7 bits
#define NBLK 256  // edge-chunk blocks for binning
#define RCAP 8192 // LDS record capacity in k_csr

__device__ __forceinline__ float lrelu(float x) { return x > 0.f ? x : NEG_SLOPE * x; }

// ---------------------------------------------------------------------------
// K1: h1 = x @ W1 (50000x256 @ 256x64) tiled GEMM + fused alpha_src/alpha_dst.
// h1 stored as fp16; alphas stay f32.
// ---------------------------------------------------------------------------
__global__ __launch_bounds__(256) void k_gemm1(
    const float* __restrict__ x, const float* __restrict__ W,
    const float* __restrict__ a_src, const float* __restrict__ a_dst,
    __half* __restrict__ h1h, float* __restrict__ as1, float* __restrict__ ad1,
    int N)
{
    __shared__ float xl[BM][LS];
    __shared__ float wl[KB][LS];
    const int t  = threadIdx.x;
    const int tx = t & 15;
    const int ty = t >> 4;
    const int row0 = blockIdx.x * BM;

    float acc[4][4] = {};

    for (int kc = 0; kc < NF; kc += KB) {
        #pragma unroll
        for (int i = 0; i < 4; ++i) {
            int r = (t >> 4) + 16 * i;
            int row = row0 + r; if (row >= N) row = N - 1;
            float4 v = *(const float4*)(x + (size_t)row * NF + kc + 4 * tx);
            *(float4*)&xl[r][4 * tx] = v;
        }
        #pragma unroll
        for (int i = 0; i < 4; ++i) {
            int k = (t >> 4) + 16 * i;
            float4 v = *(const float4*)(W + (size_t)(kc + k) * NO + 4 * tx);
            *(float4*)&wl[k][4 * tx] = v;
        }
        __syncthreads();

        #pragma unroll
        for (int k = 0; k < KB; k += 4) {
            float4 xv[4], wv[4];
            #pragma unroll
            for (int r = 0; r < 4; ++r)
                xv[r] = *(const float4*)&xl[4 * ty + r][k];
            #pragma unroll
            for (int kk = 0; kk < 4; ++kk)
                wv[kk] = *(const float4*)&wl[k + kk][4 * tx];
            #pragma unroll
            for (int r = 0; r < 4; ++r) {
                float4 xr = xv[r];
                #pragma unroll
                for (int kk = 0; kk < 4; ++kk) {
                    float xk = (kk == 0) ? xr.x : (kk == 1) ? xr.y : (kk == 2) ? xr.z : xr.w;
                    acc[r][0] = fmaf(xk, wv[kk].x, acc[r][0]);
                    acc[r][1] = fmaf(xk, wv[kk].y, acc[r][1]);
                    acc[r][2] = fmaf(xk, wv[kk].z, acc[r][2]);
                    acc[r][3] = fmaf(xk, wv[kk].w, acc[r][3]);
                }
            }
        }
        __syncthreads();
    }

    const float4 avs = *(const float4*)(a_src + 4 * tx);
    const float4 avd = *(const float4*)(a_dst + 4 * tx);
    #pragma unroll
    for (int r = 0; r < 4; ++r) {
        int row = row0 + 4 * ty + r;
        if (row >= N) continue;
        float4 o = make_float4(acc[r][0], acc[r][1], acc[r][2], acc[r][3]);
        __half2 p0 = __float22half2_rn(make_float2(o.x, o.y));
        __half2 p1 = __float22half2_rn(make_float2(o.z, o.w));
        __half2* dst2 = (__half2*)(h1h + (size_t)row * NO + 4 * tx);
        dst2[0] = p0;
        dst2[1] = p1;
        float vs = o.x * avs.x + o.y * avs.y + o.z * avs.z + o.w * avs.w;
        float vd = o.x * avd.x + o.y * avd.y + o.z * avd.z + o.w * avd.w;
        vs += __shfl_xor(vs, 1);
        vd += __shfl_xor(vd, 1);
        if ((tx & 1) == 0) {
            as1[row * NHEAD + (tx >> 1)] = vs;
            ad1[row * NHEAD + (tx >> 1)] = vd;
        }
    }
}

// ---------------------------------------------------------------------------
// B1: per-chunk-block bucket histogram (LDS atomics) -> M[b][blk], totals T[b]
// ---------------------------------------------------------------------------
__global__ __launch_bounds__(256) void k_bhist(
    const int* __restrict__ eidx, int E, int N, int NB, int CH,
    unsigned* __restrict__ M, unsigned* __restrict__ T)
{
    __shared__ unsigned hist[512];
    for (int i = threadIdx.x; i < NB; i += 256) hist[i] = 0;
    __syncthreads();
    const int blk = blockIdx.x;
    const int lo = blk * CH;
    const int hi = min(lo + CH, E + N);
    for (int i = lo + (int)threadIdx.x; i < hi; i += 256) {
        int d = (i < E) ? eidx[E + i] : (i - E);
        atomicAdd(&hist[d >> 7], 1u);
    }
    __syncthreads();
    for (int b = threadIdx.x; b < NB; b += 256) {
        unsigned c = hist[b];
        M[(size_t)b * NBLK + blk] = c;
        if (c) atomicAdd(&T[b], c);
    }
}

// ---------------------------------------------------------------------------
// B2: exclusive scan of bucket totals T -> Bbase[0..NB]  (single block)
// ---------------------------------------------------------------------------
__global__ __launch_bounds__(512) void k_btot(
    const unsigned* __restrict__ T, unsigned* __restrict__ Bbase, int NB)
{
    __shared__ unsigned ws[8];
    const int t = threadIdx.x, lane = t & 63, w = t >> 6;
    unsigned v = (t < NB) ? T[t] : 0u;
    unsigned p = v;
    #pragma unroll
    for (int d = 1; d < 64; d <<= 1) {
        unsigned q = __shfl_up(p, d);
        if (lane >= d) p += q;
    }
    if (lane == 63) ws[w] = p;
    __syncthreads();
    unsigned wb = 0;
    for (int j = 0; j < w; ++j) wb += ws[j];
    if (t <= NB) Bbase[t] = wb + p - v;
}

// ---------------------------------------------------------------------------
// B3: per-bucket exclusive scan of M row (+ bucket base) -> scatter cursors
// ---------------------------------------------------------------------------
__global__ __launch_bounds__(256) void k_bscan3(
    unsigned* __restrict__ M, const unsigned* __restrict__ Bbase, int NB)
{
    __shared__ unsigned ws[4];
    const int b = blockIdx.x;
    const int lane = threadIdx.x & 63, w = threadIdx.x >> 6;
    unsigned v = M[(size_t)b * NBLK + threadIdx.x];
    unsigned p = v;
    #pragma unroll
    for (int d = 1; d < 64; d <<= 1) {
        unsigned q = __shfl_up(p, d);
        if (lane >= d) p += q;
    }
    if (lane == 63) ws[w] = p;
    __syncthreads();
    unsigned wb = 0;
    for (int j = 0; j < w; ++j) wb += ws[j];
    M[(size_t)b * NBLK + threadIdx.x] = Bbase[b] + wb + p - v;
}

// ---------------------------------------------------------------------------
// B4: scatter packed records (s<<7 | d_local) into bucket-contiguous regions.
// ---------------------------------------------------------------------------
__global__ __launch_bounds__(256) void k_bscatter(
    const int* __restrict__ eidx, int E, int N, int NB, int CH,
    const unsigned* __restrict__ M, unsigned* __restrict__ rbuf)
{
    __shared__ unsigned cur[512];
    const int blk = blockIdx.x;
    for (int b = threadIdx.x; b < NB; b += 256)
        cur[b] = M[(size_t)b * NBLK + blk];
    __syncthreads();
    const int lo = blk * CH;
    const int hi = min(lo + CH, E + N);
    for (int i = lo + (int)threadIdx.x; i < hi; i += 256) {
        int s, d;
        if (i < E) { s = eidx[i]; d = eidx[E + i]; }
        else       { s = i - E;   d = i - E; }
        unsigned pos = atomicAdd(&cur[d >> 7], 1u);
        rbuf[pos] = ((unsigned)s << 7) | (unsigned)(d & (BKT - 1));
    }
}

// ---------------------------------------------------------------------------
// B5: per-bucket LDS counting sort -> node-ordered csr (in place) + offs.
// ---------------------------------------------------------------------------
__global__ __launch_bounds__(256) void k_csr(
    const unsigned* __restrict__ Bbase, int N, int NB,
    unsigned* __restrict__ rbuf, unsigned* __restrict__ offs)
{
    __shared__ unsigned recs[RCAP];
    __shared__ unsigned nhist[BKT];
    __shared__ unsigned ncur[BKT];
    __shared__ unsigned wtotS;
    const int b = blockIdx.x;
    const unsigned base = Bbase[b], end = Bbase[b + 1];
    const int cnt = (int)(end - base);
    const int nodes = min(BKT, N - b * BKT);

    for (int i = threadIdx.x; i < BKT; i += 256) nhist[i] = 0;
    __syncthreads();
    for (int i = threadIdx.x; i < cnt; i += 256) {
        unsigned r = rbuf[base + i];
        recs[i] = r;
        atomicAdd(&nhist[r & (BKT - 1)], 1u);
    }
    __syncthreads();
    const int tl = threadIdx.x & 127;
    unsigned v = nhist[tl], p = v;
    #pragma unroll
    for (int d = 1; d < 64; d <<= 1) {
        unsigned q = __shfl_up(p, d);
        if ((tl & 63) >= d) p += q;
    }
    if (threadIdx.x == 63) wtotS = p;
    __syncthreads();
    unsigned excl = base + ((tl >= 64) ? wtotS : 0u) + p - v;
    if (threadIdx.x < 128) {
        ncur[tl] = excl;
        if (tl < nodes) offs[b * BKT + tl] = excl;
    }
    if (b == NB - 1 && threadIdx.x == 0) offs[N] = end;
    __syncthreads();
    for (int i = threadIdx.x; i < cnt; i += 256) {
        unsigned r = recs[i];
        unsigned pos = atomicAdd(&ncur[r & (BKT - 1)], 1u);
        rbuf[pos] = r >> 7;
    }
}

// ---------------------------------------------------------------------------
// K5: layer-1 GAT aggregation. One wave per dst node, 8 lanes/edge:
// lane = (slot = lane>>3, head = lane&7); lane covers the 8 channels of its
// head via one dwordx4 fp16 load. exp/lrelu computed ONCE per (edge,head).
// Slot-reduce (xor 8/16/32), per-head epilogue, head-reduce (xor 1/2/4)
// for the fused W2 projection.
// ---------------------------------------------------------------------------
__global__ __launch_bounds__(256) void k_gat1(
    const unsigned* __restrict__ offs, const int* __restrict__ csr,
    const float4* __restrict__ h1q,   // h1 as float4 units: 8 per node row
    const float* __restrict__ as1, const float* __restrict__ ad1,
    const float* __restrict__ b1, const float* __restrict__ W2,
    float* __restrict__ h2, int N)
{
    const int lane = threadIdx.x & 63;
    const int n = blockIdx.x * (blockDim.x >> 6) + (threadIdx.x >> 6);
    if (n >= N) return;
    const int slot = lane >> 3;
    const int head = lane & 7;
    const unsigned s0 = offs[n];
    const unsigned deg = offs[n + 1] - s0;
    const float ad = ad1[n * NHEAD + head];

    float acc[8] = {};
    float den = 0.f;

    unsigned k = (unsigned)slot;
    for (; k + 8 < deg; k += 16) {       // 2 edges in flight per lane
        int sA = csr[s0 + k], sB = csr[s0 + k + 8];
        float aA = as1[sA * NHEAD + head];
        float aB = as1[sB * NHEAD + head];
        float4 rA = h1q[(unsigned)sA * 8u + head];
        float4 rB = h1q[(unsigned)sB * 8u + head];
        float pA = __expf(lrelu(aA + ad));
        float pB = __expf(lrelu(aB + ad));
        den += pA + pB;
        const __half2* hA = (const __half2*)&rA;
        const __half2* hB = (const __half2*)&rB;
        #pragma unroll
        for (int j = 0; j < 4; ++j) {
            float2 fA = __half22float2(hA[j]);
            float2 fB = __half22float2(hB[j]);
            acc[2 * j]     = fmaf(pA, fA.x, acc[2 * j]);
            acc[2 * j + 1] = fmaf(pA, fA.y, acc[2 * j + 1]);
            acc[2 * j]     = fmaf(pB, fB.x, acc[2 * j]);
            acc[2 * j + 1] = fmaf(pB, fB.y, acc[2 * j + 1]);
        }
    }
    if (k < deg) {
        int s = csr[s0 + k];
        float a = as1[s * NHEAD + head];
        float4 r = h1q[(unsigned)s * 8u + head];
        float p = __expf(lrelu(a + ad));
        den += p;
        const __half2* hh = (const __half2*)&r;
        #pragma unroll
        for (int j = 0; j < 4; ++j) {
            float2 f = __half22float2(hh[j]);
            acc[2 * j]     = fmaf(p, f.x, acc[2 * j]);
            acc[2 * j + 1] = fmaf(p, f.y, acc[2 * j + 1]);
        }
    }

    // reduce over edge-slots (lane bits 3..5)
    #pragma unroll
    for (int r = 0; r < 8; ++r) {
        acc[r] += __shfl_xor(acc[r], 8);
        acc[r] += __shfl_xor(acc[r], 16);
        acc[r] += __shfl_xor(acc[r], 32);
    }
    den += __shfl_xor(den, 8);
    den += __shfl_xor(den, 16);
    den += __shfl_xor(den, 32);

    // per-head epilogue: out = relu(acc/den + b1), tt = out . W2 (head's 8 ch)
    const float4 b0 = ((const float4*)b1)[head * 2];
    const float4 b1v = ((const float4*)b1)[head * 2 + 1];
    const float4 w0 = ((const float4*)W2)[head * 2];
    const float4 w1v = ((const float4*)W2)[head * 2 + 1];
    const float inv = 1.f / den;
    float tt = 0.f;
    tt += fmaxf(fmaf(acc[0], inv, b0.x), 0.f) * w0.x;
    tt += fmaxf(fmaf(acc[1], inv, b0.y), 0.f) * w0.y;
    tt += fmaxf(fmaf(acc[2], inv, b0.z), 0.f) * w0.z;
    tt += fmaxf(fmaf(acc[3], inv, b0.w), 0.f) * w0.w;
    tt += fmaxf(fmaf(acc[4], inv, b1v.x), 0.f) * w1v.x;
    tt += fmaxf(fmaf(acc[5], inv, b1v.y), 0.f) * w1v.y;
    tt += fmaxf(fmaf(acc[6], inv, b1v.z), 0.f) * w1v.z;
    tt += fmaxf(fmaf(acc[7], inv, b1v.w), 0.f) * w1v.w;
    // reduce over heads (lane bits 0..2)
    tt += __shfl_xor(tt, 1);
    tt += __shfl_xor(tt, 2);
    tt += __shfl_xor(tt, 4);
    if (lane == 0) h2[n] = tt;
}

// ---------------------------------------------------------------------------
// K6: layer-2 GAT (1 head, scalar). 16 lanes per node (4 nodes/wave) —
// avg deg 33 left half a 64-lane wave idle. No max pass (shift-invariant
// softmax, |e| small, f32-safe).
// ---------------------------------------------------------------------------
__global__ __launch_bounds__(256) void k_gat2(
    const unsigned* __restrict__ offs, const int* __restrict__ csr,
    const float* __restrict__ h2, const float* __restrict__ a_src2,
    const float* __restrict__ a_dst2, const float* __restrict__ b2,
    float* __restrict__ onode, int N)
{
    const int lane = threadIdx.x & 63;
    const int ql = lane & 15;            // lane within node group
    const int n = (blockIdx.x * (blockDim.x >> 6) + (threadIdx.x >> 6)) * 4
                  + (lane >> 4);
    if (n >= N) return;
    const float aS = a_src2[0], aD = a_dst2[0];
    const unsigned s0 = offs[n], s1 = offs[n + 1];
    const float ad = h2[n] * aD;

    float num = 0.f, den = 0.f;
    for (unsigned j = s0 + (unsigned)ql; j < s1; j += 16) {
        float hs = h2[csr[j]];
        float p = __expf(lrelu(hs * aS + ad));
        num = fmaf(p, hs, num);
        den += p;
    }
    #pragma unroll
    for (int msk = 1; msk < 16; msk <<= 1) {
        num += __shfl_xor(num, msk);
        den += __shfl_xor(den, msk);
    }
    if (ql == 0) onode[n] = num / den + b2[0];
}

// ---------------------------------------------------------------------------
// K6b: mean-pool over sorted batch: one atomic pair per wave + rare boundary.
// ---------------------------------------------------------------------------
__global__ __launch_bounds__(256) void k_pool(
    const float* __restrict__ onode, const int* __restrict__ batch,
    float* __restrict__ gsum, float* __restrict__ gcnt, int N)
{
    const int lane = threadIdx.x & 63;
    const int base = (blockIdx.x * (blockDim.x >> 6) + (threadIdx.x >> 6)) * 64;
    if (base >= N) return;
    const int n = base + lane;
    const bool act = (n < N);
    float o = 0.f;
    int g = -1;
    if (act) { o = onode[n]; g = batch[n]; }
    const int g0 = __shfl(g, 0);
    const bool same = (g == g0);
    float s = (act && same) ? o : 0.f;
    float c = (act && same) ? 1.f : 0.f;
    #pragma unroll
    for (int msk = 1; msk < 64; msk <<= 1) {
        s += __shfl_xor(s, msk);
        c += __shfl_xor(c, msk);
    }
    if (lane == 0) {
        unsafeAtomicAdd(&gsum[g0], s);
        unsafeAtomicAdd(&gcnt[g0], c);
    }
    if (act && !same) {
        unsafeAtomicAdd(&gsum[g], o);
        unsafeAtomicAdd(&gcnt[g], 1.0f);
    }
}

// ---------------------------------------------------------------------------
// K7: final per-graph mean
// ---------------------------------------------------------------------------
__global__ void k_final(const float* __restrict__ gsum,
                        const float* __restrict__ gcnt,
                        float* __restrict__ out, int G)
{
    int g = blockIdx.x * blockDim.x + threadIdx.x;
    if (g < G) out[g] = gsum[g] / fmaxf(gcnt[g], 1.0f);
}

// ---------------------------------------------------------------------------
extern "C" void kernel_launch(void* const* d_in, const int* in_sizes, int n_in,
                              void* d_out, int out_size, void* d_ws, size_t ws_size,
                              hipStream_t stream)
{
    const float* x      = (const float*)d_in[0];
    const int*   eidx   = (const int*)d_in[1];
    const int*   batch  = (const int*)d_in[2];
    const float* W1     = (const float*)d_in[3];
    const float* a_src1 = (const float*)d_in[4];
    const float* a_dst1 = (const float*)d_in[5];
    const float* b1     = (const float*)d_in[6];
    const float* W2     = (const float*)d_in[7];
    const float* a_src2 = (const float*)d_in[8];
    const float* a_dst2 = (const float*)d_in[9];
    const float* b2     = (const float*)d_in[10];

    const int N = in_sizes[0] / NF;      // 50000
    const int E = in_sizes[1] / 2;       // 1600000
    const int G = out_size;              // 64
    const int ETOT = E + N;
    const int NB = (N + BKT - 1) / BKT;  // 391 buckets
    const int CH = (ETOT + NBLK - 1) / NBLK;

    // workspace layout (bytes)
    char* w = (char*)d_ws;
    __half*   h1h   = (__half*)(w + 0);           //  6,400,000 (fp16)
    float*    as1   = (float*)(w + 6400000);      //  1,600,000
    float*    ad1   = (float*)(w + 8000000);      //  1,600,000
    float*    h2    = (float*)(w + 9600000);      //    200,000
    unsigned* offs  = (unsigned*)(w + 9800000);   //    200,064
    unsigned* rbuf  = (unsigned*)(w + 10000064);  //  6,600,000 (records -> csr)
    unsigned* M     = (unsigned*)(w + 16600064);  //    400,384
    unsigned* T     = (unsigned*)(w + 17000448);  //      2,048
    unsigned* Bbase = (unsigned*)(w + 17002496);  //      2,048
    float*    gsum  = (float*)(w + 17004544);     //        256
    float*    gcnt  = (float*)(w + 17004800);     //        256
    float*    onode = (float*)(w + 17005056);     //    200,000

    hipMemsetAsync(T, 0, (size_t)(NB + 1) * 4, stream);
    hipMemsetAsync(gsum, 0, 512, stream);  // gsum + gcnt

    k_gemm1<<<(N + BM - 1) / BM, 256, 0, stream>>>(x, W1, a_src1, a_dst1,
                                                   h1h, as1, ad1, N);

    k_bhist<<<NBLK, 256, 0, stream>>>(eidx, E, N, NB, CH, M, T);
    k_btot<<<1, 512, 0, stream>>>(T, Bbase, NB);
    k_bscan3<<<NB, 256, 0, stream>>>(M, Bbase, NB);
    k_bscatter<<<NBLK, 256, 0, stream>>>(eidx, E, N, NB, CH, M, rbuf);
    k_csr<<<NB, 256, 0, stream>>>(Bbase, N, NB, rbuf, offs);

    const int* csr = (const int*)rbuf;
    k_gat1<<<(N + 3) / 4, 256, 0, stream>>>(offs, csr, (const float4*)h1h,
                                            as1, ad1, b1, W2, h2, N);
    k_gat2<<<(N + 15) / 16, 256, 0, stream>>>(offs, csr, h2, a_src2, a_dst2, b2,
                                              onode, N);
    int pw = (N + 63) / 64;
    k_pool<<<(pw + 3) / 4, 256, 0, stream>>>(onode, batch, gsum, gcnt, N);
    k_final<<<1, 64, 0, stream>>>(gsum, gcnt, (float*)d_out, G);
}

// Round 7
// 146.849 us; speedup vs baseline: 7.8546x; 1.0558x over previous
//
#include <hip/hip_runtime.h>
#include <hip/hip_bf16.h>
#include <hip/hip_fp16.h>
#include <math.h>

#define NF 256    // input features
#define NO 64     // heads*c1 = 8*8
#define NHEAD 8
#define NEG_SLOPE 0.2f
#define BM 64     // gemm row tile
#define KB 64     // gemm k tile
#define LS 68     // gemm LDS row stride
#define BKT 128   // nodes per dst-bucket (d>>7); d_local = 7 bits
#define NBLK 256  // edge-chunk blocks for binning
#define RCAP 8192 // LDS record capacity in k_csr

__device__ __forceinline__ float lrelu(float x) { return x > 0.f ? x : NEG_SLOPE * x; }

// ---------------------------------------------------------------------------
// K1: h1 = x @ W1 (50000x256 @ 256x64) tiled GEMM + fused alpha_src/alpha_dst.
// h1 stored as fp16; alphas stay f32. Block 0 additionally zeroes the small
// accumulator buffers (T, gsum, gcnt) — replaces two hipMemsetAsync graph
// nodes that each cost ~40us/replay.
// ---------------------------------------------------------------------------
__global__ __launch_bounds__(256) void k_gemm1(
    const float* __restrict__ x, const float* __restrict__ W,
    const float* __restrict__ a_src, const float* __restrict__ a_dst,
    __half* __restrict__ h1h, float* __restrict__ as1, float* __restrict__ ad1,
    unsigned* __restrict__ T, float* __restrict__ gsum, float* __restrict__ gcnt,
    int N)
{
    if (blockIdx.x == 0) {
        for (int i = threadIdx.x; i < 512; i += 256) T[i] = 0u;
        if (threadIdx.x < 64) { gsum[threadIdx.x] = 0.f; gcnt[threadIdx.x] = 0.f; }
    }

    __shared__ float xl[BM][LS];
    __shared__ float wl[KB][LS];
    const int t  = threadIdx.x;
    const int tx = t & 15;
    const int ty = t >> 4;
    const int row0 = blockIdx.x * BM;

    float acc[4][4] = {};

    for (int kc = 0; kc < NF; kc += KB) {
        #pragma unroll
        for (int i = 0; i < 4; ++i) {
            int r = (t >> 4) + 16 * i;
            int row = row0 + r; if (row >= N) row = N - 1;
            float4 v = *(const float4*)(x + (size_t)row * NF + kc + 4 * tx);
            *(float4*)&xl[r][4 * tx] = v;
        }
        #pragma unroll
        for (int i = 0; i < 4; ++i) {
            int k = (t >> 4) + 16 * i;
            float4 v = *(const float4*)(W + (size_t)(kc + k) * NO + 4 * tx);
            *(float4*)&wl[k][4 * tx] = v;
        }
        __syncthreads();

        #pragma unroll
        for (int k = 0; k < KB; k += 4) {
            float4 xv[4], wv[4];
            #pragma unroll
            for (int r = 0; r < 4; ++r)
                xv[r] = *(const float4*)&xl[4 * ty + r][k];
            #pragma unroll
            for (int kk = 0; kk < 4; ++kk)
                wv[kk] = *(const float4*)&wl[k + kk][4 * tx];
            #pragma unroll
            for (int r = 0; r < 4; ++r) {
                float4 xr = xv[r];
                #pragma unroll
                for (int kk = 0; kk < 4; ++kk) {
                    float xk = (kk == 0) ? xr.x : (kk == 1) ? xr.y : (kk == 2) ? xr.z : xr.w;
                    acc[r][0] = fmaf(xk, wv[kk].x, acc[r][0]);
                    acc[r][1] = fmaf(xk, wv[kk].y, acc[r][1]);
                    acc[r][2] = fmaf(xk, wv[kk].z, acc[r][2]);
                    acc[r][3] = fmaf(xk, wv[kk].w, acc[r][3]);
                }
            }
        }
        __syncthreads();
    }

    const float4 avs = *(const float4*)(a_src + 4 * tx);
    const float4 avd = *(const float4*)(a_dst + 4 * tx);
    #pragma unroll
    for (int r = 0; r < 4; ++r) {
        int row = row0 + 4 * ty + r;
        if (row >= N) continue;
        float4 o = make_float4(acc[r][0], acc[r][1], acc[r][2], acc[r][3]);
        __half2 p0 = __float22half2_rn(make_float2(o.x, o.y));
        __half2 p1 = __float22half2_rn(make_float2(o.z, o.w));
        __half2* dst2 = (__half2*)(h1h + (size_t)row * NO + 4 * tx);
        dst2[0] = p0;
        dst2[1] = p1;
        float vs = o.x * avs.x + o.y * avs.y + o.z * avs.z + o.w * avs.w;
        float vd = o.x * avd.x + o.y * avd.y + o.z * avd.z + o.w * avd.w;
        vs += __shfl_xor(vs, 1);
        vd += __shfl_xor(vd, 1);
        if ((tx & 1) == 0) {
            as1[row * NHEAD + (tx >> 1)] = vs;
            ad1[row * NHEAD + (tx >> 1)] = vd;
        }
    }
}

// ---------------------------------------------------------------------------
// B1: per-chunk-block bucket histogram (LDS atomics) -> M[b][blk], totals T[b]
// ---------------------------------------------------------------------------
__global__ __launch_bounds__(256) void k_bhist(
    const int* __restrict__ eidx, int E, int N, int NB, int CH,
    unsigned* __restrict__ M, unsigned* __restrict__ T)
{
    __shared__ unsigned hist[512];
    for (int i = threadIdx.x; i < NB; i += 256) hist[i] = 0;
    __syncthreads();
    const int blk = blockIdx.x;
    const int lo = blk * CH;
    const int hi = min(lo + CH, E + N);
    for (int i = lo + (int)threadIdx.x; i < hi; i += 256) {
        int d = (i < E) ? eidx[E + i] : (i - E);
        atomicAdd(&hist[d >> 7], 1u);
    }
    __syncthreads();
    for (int b = threadIdx.x; b < NB; b += 256) {
        unsigned c = hist[b];
        M[(size_t)b * NBLK + blk] = c;
        if (c) atomicAdd(&T[b], c);
    }
}

// ---------------------------------------------------------------------------
// B2: exclusive scan of bucket totals T -> Bbase[0..NB]  (single block)
// ---------------------------------------------------------------------------
__global__ __launch_bounds__(512) void k_btot(
    const unsigned* __restrict__ T, unsigned* __restrict__ Bbase, int NB)
{
    __shared__ unsigned ws[8];
    const int t = threadIdx.x, lane = t & 63, w = t >> 6;
    unsigned v = (t < NB) ? T[t] : 0u;
    unsigned p = v;
    #pragma unroll
    for (int d = 1; d < 64; d <<= 1) {
        unsigned q = __shfl_up(p, d);
        if (lane >= d) p += q;
    }
    if (lane == 63) ws[w] = p;
    __syncthreads();
    unsigned wb = 0;
    for (int j = 0; j < w; ++j) wb += ws[j];
    if (t <= NB) Bbase[t] = wb + p - v;
}

// ---------------------------------------------------------------------------
// B3: per-bucket exclusive scan of M row (+ bucket base) -> scatter cursors
// ---------------------------------------------------------------------------
__global__ __launch_bounds__(256) void k_bscan3(
    unsigned* __restrict__ M, const unsigned* __restrict__ Bbase, int NB)
{
    __shared__ unsigned ws[4];
    const int b = blockIdx.x;
    const int lane = threadIdx.x & 63, w = threadIdx.x >> 6;
    unsigned v = M[(size_t)b * NBLK + threadIdx.x];
    unsigned p = v;
    #pragma unroll
    for (int d = 1; d < 64; d <<= 1) {
        unsigned q = __shfl_up(p, d);
        if (lane >= d) p += q;
    }
    if (lane == 63) ws[w] = p;
    __syncthreads();
    unsigned wb = 0;
    for (int j = 0; j < w; ++j) wb += ws[j];
    M[(size_t)b * NBLK + threadIdx.x] = Bbase[b] + wb + p - v;
}

// ---------------------------------------------------------------------------
// B4: scatter packed records (s<<7 | d_local) into bucket-contiguous regions.
// ---------------------------------------------------------------------------
__global__ __launch_bounds__(256) void k_bscatter(
    const int* __restrict__ eidx, int E, int N, int NB, int CH,
    const unsigned* __restrict__ M, unsigned* __restrict__ rbuf)
{
    __shared__ unsigned cur[512];
    const int blk = blockIdx.x;
    for (int b = threadIdx.x; b < NB; b += 256)
        cur[b] = M[(size_t)b * NBLK + blk];
    __syncthreads();
    const int lo = blk * CH;
    const int hi = min(lo + CH, E + N);
    for (int i = lo + (int)threadIdx.x; i < hi; i += 256) {
        int s, d;
        if (i < E) { s = eidx[i]; d = eidx[E + i]; }
        else       { s = i - E;   d = i - E; }
        unsigned pos = atomicAdd(&cur[d >> 7], 1u);
        rbuf[pos] = ((unsigned)s << 7) | (unsigned)(d & (BKT - 1));
    }
}

// ---------------------------------------------------------------------------
// B5: per-bucket LDS counting sort -> node-ordered csr (in place) + offs.
// ---------------------------------------------------------------------------
__global__ __launch_bounds__(256) void k_csr(
    const unsigned* __restrict__ Bbase, int N, int NB,
    unsigned* __restrict__ rbuf, unsigned* __restrict__ offs)
{
    __shared__ unsigned recs[RCAP];
    __shared__ unsigned nhist[BKT];
    __shared__ unsigned ncur[BKT];
    __shared__ unsigned wtotS;
    const int b = blockIdx.x;
    const unsigned base = Bbase[b], end = Bbase[b + 1];
    const int cnt = (int)(end - base);
    const int nodes = min(BKT, N - b * BKT);

    for (int i = threadIdx.x; i < BKT; i += 256) nhist[i] = 0;
    __syncthreads();
    for (int i = threadIdx.x; i < cnt; i += 256) {
        unsigned r = rbuf[base + i];
        recs[i] = r;
        atomicAdd(&nhist[r & (BKT - 1)], 1u);
    }
    __syncthreads();
    const int tl = threadIdx.x & 127;
    unsigned v = nhist[tl], p = v;
    #pragma unroll
    for (int d = 1; d < 64; d <<= 1) {
        unsigned q = __shfl_up(p, d);
        if ((tl & 63) >= d) p += q;
    }
    if (threadIdx.x == 63) wtotS = p;
    __syncthreads();
    unsigned excl = base + ((tl >= 64) ? wtotS : 0u) + p - v;
    if (threadIdx.x < 128) {
        ncur[tl] = excl;
        if (tl < nodes) offs[b * BKT + tl] = excl;
    }
    if (b == NB - 1 && threadIdx.x == 0) offs[N] = end;
    __syncthreads();
    for (int i = threadIdx.x; i < cnt; i += 256) {
        unsigned r = recs[i];
        unsigned pos = atomicAdd(&ncur[r & (BKT - 1)], 1u);
        rbuf[pos] = r >> 7;
    }
}

// ---------------------------------------------------------------------------
// K5: layer-1 GAT aggregation. One wave per dst node, 8 lanes/edge:
// lane = (slot = lane>>3, head = lane&7). exp/lrelu once per (edge,head).
// 4 edges in flight per lane (4->2->1 tail) for memory-level parallelism.
// ---------------------------------------------------------------------------
__global__ __launch_bounds__(256) void k_gat1(
    const unsigned* __restrict__ offs, const int* __restrict__ csr,
    const float4* __restrict__ h1q,   // h1 as float4 units: 8 per node row
    const float* __restrict__ as1, const float* __restrict__ ad1,
    const float* __restrict__ b1, const float* __restrict__ W2,
    float* __restrict__ h2, int N)
{
    const int lane = threadIdx.x & 63;
    const int n = blockIdx.x * (blockDim.x >> 6) + (threadIdx.x >> 6);
    if (n >= N) return;
    const int slot = lane >> 3;
    const int head = lane & 7;
    const unsigned s0 = offs[n];
    const unsigned deg = offs[n + 1] - s0;
    const float ad = ad1[n * NHEAD + head];

    float acc[8] = {};
    float den = 0.f;

    unsigned k = (unsigned)slot;
    for (; k + 24 < deg; k += 32) {      // 4 edges in flight per lane
        int sA = csr[s0 + k],      sB = csr[s0 + k + 8];
        int sC = csr[s0 + k + 16], sD = csr[s0 + k + 24];
        float aA = as1[sA * NHEAD + head], aB = as1[sB * NHEAD + head];
        float aC = as1[sC * NHEAD + head], aD = as1[sD * NHEAD + head];
        float4 rA = h1q[(unsigned)sA * 8u + head];
        float4 rB = h1q[(unsigned)sB * 8u + head];
        float4 rC = h1q[(unsigned)sC * 8u + head];
        float4 rD = h1q[(unsigned)sD * 8u + head];
        float pA = __expf(lrelu(aA + ad));
        float pB = __expf(lrelu(aB + ad));
        float pC = __expf(lrelu(aC + ad));
        float pD = __expf(lrelu(aD + ad));
        den += (pA + pB) + (pC + pD);
        const __half2* hA = (const __half2*)&rA;
        const __half2* hB = (const __half2*)&rB;
        const __half2* hC = (const __half2*)&rC;
        const __half2* hD = (const __half2*)&rD;
        #pragma unroll
        for (int j = 0; j < 4; ++j) {
            float2 fA = __half22float2(hA[j]);
            float2 fB = __half22float2(hB[j]);
            float2 fC = __half22float2(hC[j]);
            float2 fD = __half22float2(hD[j]);
            acc[2 * j]     = fmaf(pA, fA.x, acc[2 * j]);
            acc[2 * j + 1] = fmaf(pA, fA.y, acc[2 * j + 1]);
            acc[2 * j]     = fmaf(pB, fB.x, acc[2 * j]);
            acc[2 * j + 1] = fmaf(pB, fB.y, acc[2 * j + 1]);
            acc[2 * j]     = fmaf(pC, fC.x, acc[2 * j]);
            acc[2 * j + 1] = fmaf(pC, fC.y, acc[2 * j + 1]);
            acc[2 * j]     = fmaf(pD, fD.x, acc[2 * j]);
            acc[2 * j + 1] = fmaf(pD, fD.y, acc[2 * j + 1]);
        }
    }
    for (; k + 8 < deg; k += 16) {       // 2 edges in flight
        int sA = csr[s0 + k], sB = csr[s0 + k + 8];
        float aA = as1[sA * NHEAD + head], aB = as1[sB * NHEAD + head];
        float4 rA = h1q[(unsigned)sA * 8u + head];
        float4 rB = h1q[(unsigned)sB * 8u + head];
        float pA = __expf(lrelu(aA + ad));
        float pB = __expf(lrelu(aB + ad));
        den += pA + pB;
        const __half2* hA = (const __half2*)&rA;
        const __half2* hB = (const __half2*)&rB;
        #pragma unroll
        for (int j = 0; j < 4; ++j) {
            float2 fA = __half22float2(hA[j]);
            float2 fB = __half22float2(hB[j]);
            acc[2 * j]     = fmaf(pA, fA.x, acc[2 * j]);
            acc[2 * j + 1] = fmaf(pA, fA.y, acc[2 * j + 1]);
            acc[2 * j]     = fmaf(pB, fB.x, acc[2 * j]);
            acc[2 * j + 1] = fmaf(pB, fB.y, acc[2 * j + 1]);
        }
    }
    if (k < deg) {
        int s = csr[s0 + k];
        float a = as1[s * NHEAD + head];
        float4 r = h1q[(unsigned)s * 8u + head];
        float p = __expf(lrelu(a + ad));
        den += p;
        const __half2* hh = (const __half2*)&r;
        #pragma unroll
        for (int j = 0; j < 4; ++j) {
            float2 f = __half22float2(hh[j]);
            acc[2 * j]     = fmaf(p, f.x, acc[2 * j]);
            acc[2 * j + 1] = fmaf(p, f.y, acc[2 * j + 1]);
        }
    }

    // reduce over edge-slots (lane bits 3..5)
    #pragma unroll
    for (int r = 0; r < 8; ++r) {
        acc[r] += __shfl_xor(acc[r], 8);
        acc[r] += __shfl_xor(acc[r], 16);
        acc[r] += __shfl_xor(acc[r], 32);
    }
    den += __shfl_xor(den, 8);
    den += __shfl_xor(den, 16);
    den += __shfl_xor(den, 32);

    // per-head epilogue: out = relu(acc/den + b1), tt = out . W2 (head's 8 ch)
    const float4 b0 = ((const float4*)b1)[head * 2];
    const float4 b1v = ((const float4*)b1)[head * 2 + 1];
    const float4 w0 = ((const float4*)W2)[head * 2];
    const float4 w1v = ((const float4*)W2)[head * 2 + 1];
    const float inv = 1.f / den;
    float tt = 0.f;
    tt += fmaxf(fmaf(acc[0], inv, b0.x), 0.f) * w0.x;
    tt += fmaxf(fmaf(acc[1], inv, b0.y), 0.f) * w0.y;
    tt += fmaxf(fmaf(acc[2], inv, b0.z), 0.f) * w0.z;
    tt += fmaxf(fmaf(acc[3], inv, b0.w), 0.f) * w0.w;
    tt += fmaxf(fmaf(acc[4], inv, b1v.x), 0.f) * w1v.x;
    tt += fmaxf(fmaf(acc[5], inv, b1v.y), 0.f) * w1v.y;
    tt += fmaxf(fmaf(acc[6], inv, b1v.z), 0.f) * w1v.z;
    tt += fmaxf(fmaf(acc[7], inv, b1v.w), 0.f) * w1v.w;
    // reduce over heads (lane bits 0..2)
    tt += __shfl_xor(tt, 1);
    tt += __shfl_xor(tt, 2);
    tt += __shfl_xor(tt, 4);
    if (lane == 0) h2[n] = tt;
}

// ---------------------------------------------------------------------------
// K6: layer-2 GAT (1 head, scalar). 16 lanes per node (4 nodes/wave).
// ---------------------------------------------------------------------------
__global__ __launch_bounds__(256) void k_gat2(
    const unsigned* __restrict__ offs, const int* __restrict__ csr,
    const float* __restrict__ h2, const float* __restrict__ a_src2,
    const float* __restrict__ a_dst2, const float* __restrict__ b2,
    float* __restrict__ onode, int N)
{
    const int lane = threadIdx.x & 63;
    const int ql = lane & 15;
    const int n = (blockIdx.x * (blockDim.x >> 6) + (threadIdx.x >> 6)) * 4
                  + (lane >> 4);
    if (n >= N) return;
    const float aS = a_src2[0], aD = a_dst2[0];
    const unsigned s0 = offs[n], s1 = offs[n + 1];
    const float ad = h2[n] * aD;

    float num = 0.f, den = 0.f;
    for (unsigned j = s0 + (unsigned)ql; j < s1; j += 16) {
        float hs = h2[csr[j]];
        float p = __expf(lrelu(hs * aS + ad));
        num = fmaf(p, hs, num);
        den += p;
    }
    #pragma unroll
    for (int msk = 1; msk < 16; msk <<= 1) {
        num += __shfl_xor(num, msk);
        den += __shfl_xor(den, msk);
    }
    if (ql == 0) onode[n] = num / den + b2[0];
}

// ---------------------------------------------------------------------------
// K6b: mean-pool over sorted batch: one atomic pair per wave + rare boundary.
// ---------------------------------------------------------------------------
__global__ __launch_bounds__(256) void k_pool(
    const float* __restrict__ onode, const int* __restrict__ batch,
    float* __restrict__ gsum, float* __restrict__ gcnt, int N)
{
    const int lane = threadIdx.x & 63;
    const int base = (blockIdx.x * (blockDim.x >> 6) + (threadIdx.x >> 6)) * 64;
    if (base >= N) return;
    const int n = base + lane;
    const bool act = (n < N);
    float o = 0.f;
    int g = -1;
    if (act) { o = onode[n]; g = batch[n]; }
    const int g0 = __shfl(g, 0);
    const bool same = (g == g0);
    float s = (act && same) ? o : 0.f;
    float c = (act && same) ? 1.f : 0.f;
    #pragma unroll
    for (int msk = 1; msk < 64; msk <<= 1) {
        s += __shfl_xor(s, msk);
        c += __shfl_xor(c, msk);
    }
    if (lane == 0) {
        unsafeAtomicAdd(&gsum[g0], s);
        unsafeAtomicAdd(&gcnt[g0], c);
    }
    if (act && !same) {
        unsafeAtomicAdd(&gsum[g], o);
        unsafeAtomicAdd(&gcnt[g], 1.0f);
    }
}

// ---------------------------------------------------------------------------
// K7: final per-graph mean
// ---------------------------------------------------------------------------
__global__ void k_final(const float* __restrict__ gsum,
                        const float* __restrict__ gcnt,
                        float* __restrict__ out, int G)
{
    int g = blockIdx.x * blockDim.x + threadIdx.x;
    if (g < G) out[g] = gsum[g] / fmaxf(gcnt[g], 1.0f);
}

// ---------------------------------------------------------------------------
extern "C" void kernel_launch(void* const* d_in, const int* in_sizes, int n_in,
                              void* d_out, int out_size, void* d_ws, size_t ws_size,
                              hipStream_t stream)
{
    const float* x      = (const float*)d_in[0];
    const int*   eidx   = (const int*)d_in[1];
    const int*   batch  = (const int*)d_in[2];
    const float* W1     = (const float*)d_in[3];
    const float* a_src1 = (const float*)d_in[4];
    const float* a_dst1 = (const float*)d_in[5];
    const float* b1     = (const float*)d_in[6];
    const float* W2     = (const float*)d_in[7];
    const float* a_src2 = (const float*)d_in[8];
    const float* a_dst2 = (const float*)d_in[9];
    const float* b2     = (const float*)d_in[10];

    const int N = in_sizes[0] / NF;      // 50000
    const int E = in_sizes[1] / 2;       // 1600000
    const int G = out_size;              // 64
    const int ETOT = E + N;
    const int NB = (N + BKT - 1) / BKT;  // 391 buckets
    const int CH = (ETOT + NBLK - 1) / NBLK;

    // workspace layout (bytes)
    char* w = (char*)d_ws;
    __half*   h1h   = (__half*)(w + 0);           //  6,400,000 (fp16)
    float*    as1   = (float*)(w + 6400000);      //  1,600,000
    float*    ad1   = (float*)(w + 8000000);      //  1,600,000
    float*    h2    = (float*)(w + 9600000);      //    200,000
    unsigned* offs  = (unsigned*)(w + 9800000);   //    200,064
    unsigned* rbuf  = (unsigned*)(w + 10000064);  //  6,600,000 (records -> csr)
    unsigned* M     = (unsigned*)(w + 16600064);  //    400,384
    unsigned* T     = (unsigned*)(w + 17000448);  //      2,048
    unsigned* Bbase = (unsigned*)(w + 17002496);  //      2,048
    float*    gsum  = (float*)(w + 17004544);     //        256
    float*    gcnt  = (float*)(w + 17004800);     //        256
    float*    onode = (float*)(w + 17005056);     //    200,000

    // NO hipMemsetAsync here: T/gsum/gcnt are zeroed by k_gemm1 block 0
    // (two tiny memset graph nodes were costing ~40us each per replay).

    k_gemm1<<<(N + BM - 1) / BM, 256, 0, stream>>>(x, W1, a_src1, a_dst1,
                                                   h1h, as1, ad1,
                                                   T, gsum, gcnt, N);

    k_bhist<<<NBLK, 256, 0, stream>>>(eidx, E, N, NB, CH, M, T);
    k_btot<<<1, 512, 0, stream>>>(T, Bbase, NB);
    k_bscan3<<<NB, 256, 0, stream>>>(M, Bbase, NB);
    k_bscatter<<<NBLK, 256, 0, stream>>>(eidx, E, N, NB, CH, M, rbuf);
    k_csr<<<NB, 256, 0, stream>>>(Bbase, N, NB, rbuf, offs);

    const int* csr = (const int*)rbuf;
    k_gat1<<<(N + 3) / 4, 256, 0, stream>>>(offs, csr, (const float4*)h1h,
                                            as1, ad1, b1, W2, h2, N);
    k_gat2<<<(N + 15) / 16, 256, 0, stream>>>(offs, csr, h2, a_src2, a_dst2, b2,
                                              onode, N);
    int pw = (N + 63) / 64;
    k_pool<<<(pw + 3) / 4, 256, 0, stream>>>(onode, batch, gsum, gcnt, N);
    k_final<<<1, 64, 0, stream>>>(gsum, gcnt, (float*)d_out, G);
}

// Round 8
// 144.898 us; speedup vs baseline: 7.9604x; 1.0135x over previous
//
#include <hip/hip_runtime.h>
#include <hip/hip_bf16.h>
#include <hip/hip_fp16.h>
#include <math.h>

#define NF 256    // input features
#define NO 64     // heads*c1 = 8*8
#define NHEAD 8
#define NEG_SLOPE 0.2f
#define BM 64     // gemm row tile
#define KB 64     // gemm k tile
#define LS 68     // gemm LDS row stride
#define BKT 128   // nodes per dst-bucket (d>>7); d_local = 7 bits
#define NBLK 256  // edge-chunk blocks for binning
#define RCAP 8192 // LDS record capacity in k_csr

__device__ __forceinline__ float lrelu(float x) { return x > 0.f ? x : NEG_SLOPE * x; }

// ---------------------------------------------------------------------------
// K1 (fused): blocks [0,GB) = tiled GEMM h1=x@W1 (+fused alphas, fp16 store);
// blocks [GB,GB+NBLK) = per-chunk bucket histogram -> M[b][blk].
// GEMM block 0 also zeroes the padded graph accumulators (gacc).
// ---------------------------------------------------------------------------
__global__ __launch_bounds__(256) void k_front(
    const float* __restrict__ x, const float* __restrict__ W,
    const float* __restrict__ a_src, const float* __restrict__ a_dst,
    __half* __restrict__ h1h, float* __restrict__ as1, float* __restrict__ ad1,
    const int* __restrict__ eidx, unsigned* __restrict__ M,
    float* __restrict__ gacc, int N, int E, int GB, int NB, int CH)
{
    __shared__ float xl[BM][LS];
    __shared__ float wl[KB][LS];

    if (blockIdx.x >= GB) {
        // ---- histogram path ----
        unsigned* hist = (unsigned*)&xl[0][0];
        for (int i = threadIdx.x; i < NB; i += 256) hist[i] = 0;
        __syncthreads();
        const int blk = blockIdx.x - GB;
        const int lo = blk * CH;
        const int hi = min(lo + CH, E + N);
        for (int i = lo + (int)threadIdx.x; i < hi; i += 256) {
            int d = (i < E) ? eidx[E + i] : (i - E);
            atomicAdd(&hist[d >> 7], 1u);
        }
        __syncthreads();
        for (int b = threadIdx.x; b < NB; b += 256)
            M[(size_t)b * NBLK + blk] = hist[b];
        return;
    }

    // ---- GEMM path ----
    if (blockIdx.x == 0) {
        for (int i = threadIdx.x; i < 1024; i += 256) gacc[i] = 0.f;  // 64 graphs x 16
    }
    const int t  = threadIdx.x;
    const int tx = t & 15;
    const int ty = t >> 4;
    const int row0 = blockIdx.x * BM;

    float acc[4][4] = {};

    for (int kc = 0; kc < NF; kc += KB) {
        #pragma unroll
        for (int i = 0; i < 4; ++i) {
            int r = (t >> 4) + 16 * i;
            int row = row0 + r; if (row >= N) row = N - 1;
            float4 v = *(const float4*)(x + (size_t)row * NF + kc + 4 * tx);
            *(float4*)&xl[r][4 * tx] = v;
        }
        #pragma unroll
        for (int i = 0; i < 4; ++i) {
            int k = (t >> 4) + 16 * i;
            float4 v = *(const float4*)(W + (size_t)(kc + k) * NO + 4 * tx);
            *(float4*)&wl[k][4 * tx] = v;
        }
        __syncthreads();

        #pragma unroll
        for (int k = 0; k < KB; k += 4) {
            float4 xv[4], wv[4];
            #pragma unroll
            for (int r = 0; r < 4; ++r)
                xv[r] = *(const float4*)&xl[4 * ty + r][k];
            #pragma unroll
            for (int kk = 0; kk < 4; ++kk)
                wv[kk] = *(const float4*)&wl[k + kk][4 * tx];
            #pragma unroll
            for (int r = 0; r < 4; ++r) {
                float4 xr = xv[r];
                #pragma unroll
                for (int kk = 0; kk < 4; ++kk) {
                    float xk = (kk == 0) ? xr.x : (kk == 1) ? xr.y : (kk == 2) ? xr.z : xr.w;
                    acc[r][0] = fmaf(xk, wv[kk].x, acc[r][0]);
                    acc[r][1] = fmaf(xk, wv[kk].y, acc[r][1]);
                    acc[r][2] = fmaf(xk, wv[kk].z, acc[r][2]);
                    acc[r][3] = fmaf(xk, wv[kk].w, acc[r][3]);
                }
            }
        }
        __syncthreads();
    }

    const float4 avs = *(const float4*)(a_src + 4 * tx);
    const float4 avd = *(const float4*)(a_dst + 4 * tx);
    #pragma unroll
    for (int r = 0; r < 4; ++r) {
        int row = row0 + 4 * ty + r;
        if (row >= N) continue;
        float4 o = make_float4(acc[r][0], acc[r][1], acc[r][2], acc[r][3]);
        __half2 p0 = __float22half2_rn(make_float2(o.x, o.y));
        __half2 p1 = __float22half2_rn(make_float2(o.z, o.w));
        __half2* dst2 = (__half2*)(h1h + (size_t)row * NO + 4 * tx);
        dst2[0] = p0;
        dst2[1] = p1;
        float vs = o.x * avs.x + o.y * avs.y + o.z * avs.z + o.w * avs.w;
        float vd = o.x * avd.x + o.y * avd.y + o.z * avd.z + o.w * avd.w;
        vs += __shfl_xor(vs, 1);
        vd += __shfl_xor(vd, 1);
        if ((tx & 1) == 0) {
            as1[row * NHEAD + (tx >> 1)] = vs;
            ad1[row * NHEAD + (tx >> 1)] = vd;
        }
    }
}

// ---------------------------------------------------------------------------
// K2: single block, 1024 threads. (a) row-sum M -> bucket totals; (b) serial
// exclusive scan of totals -> Bbase[0..NB]; (c) per-row uint4 wave scans ->
// in-place scatter cursors in M. Replaces the old k_btot + k_bscan3 (+T).
// ---------------------------------------------------------------------------
__global__ __launch_bounds__(1024) void k_scan2(
    unsigned* __restrict__ M, unsigned* __restrict__ Bbase, int NB)
{
    __shared__ unsigned tot[512];
    __shared__ unsigned basel[513];
    const int t = threadIdx.x, lane = t & 63, w = t >> 6;  // 16 waves

    for (int b = w; b < NB; b += 16) {
        uint4 v = ((const uint4*)&M[(size_t)b * NBLK])[lane];
        unsigned s = v.x + v.y + v.z + v.w;
        #pragma unroll
        for (int m = 1; m < 64; m <<= 1) s += __shfl_xor(s, m);
        if (lane == 0) tot[b] = s;
    }
    __syncthreads();
    if (t == 0) {
        unsigned r = 0;
        for (int b = 0; b < NB; ++b) { basel[b] = r; r += tot[b]; }
        basel[NB] = r;
    }
    __syncthreads();
    for (int b = t; b <= NB; b += 1024) Bbase[b] = basel[b];
    for (int b = w; b < NB; b += 16) {
        uint4 v = ((const uint4*)&M[(size_t)b * NBLK])[lane];
        unsigned lsum = v.x + v.y + v.z + v.w;
        unsigned p = lsum;
        #pragma unroll
        for (int d = 1; d < 64; d <<= 1) {
            unsigned q = __shfl_up(p, d);
            if (lane >= d) p += q;
        }
        unsigned c0 = basel[b] + p - lsum;   // exclusive prefix
        uint4 o;
        o.x = c0;
        o.y = c0 + v.x;
        o.z = o.y + v.y;
        o.w = o.z + v.z;
        ((uint4*)&M[(size_t)b * NBLK])[lane] = o;
    }
}

// ---------------------------------------------------------------------------
// K3: scatter packed records (s<<7 | d_local) into bucket-contiguous regions.
// ---------------------------------------------------------------------------
__global__ __launch_bounds__(256) void k_bscatter(
    const int* __restrict__ eidx, int E, int N, int NB, int CH,
    const unsigned* __restrict__ M, unsigned* __restrict__ rbuf)
{
    __shared__ unsigned cur[512];
    const int blk = blockIdx.x;
    for (int b = threadIdx.x; b < NB; b += 256)
        cur[b] = M[(size_t)b * NBLK + blk];
    __syncthreads();
    const int lo = blk * CH;
    const int hi = min(lo + CH, E + N);
    for (int i = lo + (int)threadIdx.x; i < hi; i += 256) {
        int s, d;
        if (i < E) { s = eidx[i]; d = eidx[E + i]; }
        else       { s = i - E;   d = i - E; }
        unsigned pos = atomicAdd(&cur[d >> 7], 1u);
        rbuf[pos] = ((unsigned)s << 7) | (unsigned)(d & (BKT - 1));
    }
}

// ---------------------------------------------------------------------------
// K4: per-bucket LDS counting sort -> node-ordered csr (in place) + offs.
// ---------------------------------------------------------------------------
__global__ __launch_bounds__(256) void k_csr(
    const unsigned* __restrict__ Bbase, int N, int NB,
    unsigned* __restrict__ rbuf, unsigned* __restrict__ offs)
{
    __shared__ unsigned recs[RCAP];
    __shared__ unsigned nhist[BKT];
    __shared__ unsigned ncur[BKT];
    __shared__ unsigned wtotS;
    const int b = blockIdx.x;
    const unsigned base = Bbase[b], end = Bbase[b + 1];
    const int cnt = (int)(end - base);
    const int nodes = min(BKT, N - b * BKT);

    for (int i = threadIdx.x; i < BKT; i += 256) nhist[i] = 0;
    __syncthreads();
    for (int i = threadIdx.x; i < cnt; i += 256) {
        unsigned r = rbuf[base + i];
        recs[i] = r;
        atomicAdd(&nhist[r & (BKT - 1)], 1u);
    }
    __syncthreads();
    const int tl = threadIdx.x & 127;
    unsigned v = nhist[tl], p = v;
    #pragma unroll
    for (int d = 1; d < 64; d <<= 1) {
        unsigned q = __shfl_up(p, d);
        if ((tl & 63) >= d) p += q;
    }
    if (threadIdx.x == 63) wtotS = p;
    __syncthreads();
    unsigned excl = base + ((tl >= 64) ? wtotS : 0u) + p - v;
    if (threadIdx.x < 128) {
        ncur[tl] = excl;
        if (tl < nodes) offs[b * BKT + tl] = excl;
    }
    if (b == NB - 1 && threadIdx.x == 0) offs[N] = end;
    __syncthreads();
    for (int i = threadIdx.x; i < cnt; i += 256) {
        unsigned r = recs[i];
        unsigned pos = atomicAdd(&ncur[r & (BKT - 1)], 1u);
        rbuf[pos] = r >> 7;
    }
}

// ---------------------------------------------------------------------------
// K5: layer-1 GAT aggregation. One wave per dst node, 8 lanes/edge
// (slot = lane>>3, head = lane&7), exp/lrelu once per (edge,head),
// 4 edges in flight per lane. Fused epilogue: relu(acc/den+b1) . W2 -> h2.
// ---------------------------------------------------------------------------
__global__ __launch_bounds__(256) void k_gat1(
    const unsigned* __restrict__ offs, const int* __restrict__ csr,
    const float4* __restrict__ h1q,
    const float* __restrict__ as1, const float* __restrict__ ad1,
    const float* __restrict__ b1, const float* __restrict__ W2,
    float* __restrict__ h2, int N)
{
    const int lane = threadIdx.x & 63;
    const int n = blockIdx.x * (blockDim.x >> 6) + (threadIdx.x >> 6);
    if (n >= N) return;
    const int slot = lane >> 3;
    const int head = lane & 7;
    const unsigned s0 = offs[n];
    const unsigned deg = offs[n + 1] - s0;
    const float ad = ad1[n * NHEAD + head];

    float acc[8] = {};
    float den = 0.f;

    unsigned k = (unsigned)slot;
    for (; k + 24 < deg; k += 32) {
        int sA = csr[s0 + k],      sB = csr[s0 + k + 8];
        int sC = csr[s0 + k + 16], sD = csr[s0 + k + 24];
        float aA = as1[sA * NHEAD + head], aB = as1[sB * NHEAD + head];
        float aC = as1[sC * NHEAD + head], aD = as1[sD * NHEAD + head];
        float4 rA = h1q[(unsigned)sA * 8u + head];
        float4 rB = h1q[(unsigned)sB * 8u + head];
        float4 rC = h1q[(unsigned)sC * 8u + head];
        float4 rD = h1q[(unsigned)sD * 8u + head];
        float pA = __expf(lrelu(aA + ad));
        float pB = __expf(lrelu(aB + ad));
        float pC = __expf(lrelu(aC + ad));
        float pD = __expf(lrelu(aD + ad));
        den += (pA + pB) + (pC + pD);
        const __half2* hA = (const __half2*)&rA;
        const __half2* hB = (const __half2*)&rB;
        const __half2* hC = (const __half2*)&rC;
        const __half2* hD = (const __half2*)&rD;
        #pragma unroll
        for (int j = 0; j < 4; ++j) {
            float2 fA = __half22float2(hA[j]);
            float2 fB = __half22float2(hB[j]);
            float2 fC = __half22float2(hC[j]);
            float2 fD = __half22float2(hD[j]);
            acc[2 * j]     = fmaf(pA, fA.x, acc[2 * j]);
            acc[2 * j + 1] = fmaf(pA, fA.y, acc[2 * j + 1]);
            acc[2 * j]     = fmaf(pB, fB.x, acc[2 * j]);
            acc[2 * j + 1] = fmaf(pB, fB.y, acc[2 * j + 1]);
            acc[2 * j]     = fmaf(pC, fC.x, acc[2 * j]);
            acc[2 * j + 1] = fmaf(pC, fC.y, acc[2 * j + 1]);
            acc[2 * j]     = fmaf(pD, fD.x, acc[2 * j]);
            acc[2 * j + 1] = fmaf(pD, fD.y, acc[2 * j + 1]);
        }
    }
    for (; k + 8 < deg; k += 16) {
        int sA = csr[s0 + k], sB = csr[s0 + k + 8];
        float aA = as1[sA * NHEAD + head], aB = as1[sB * NHEAD + head];
        float4 rA = h1q[(unsigned)sA * 8u + head];
        float4 rB = h1q[(unsigned)sB * 8u + head];
        float pA = __expf(lrelu(aA + ad));
        float pB = __expf(lrelu(aB + ad));
        den += pA + pB;
        const __half2* hA = (const __half2*)&rA;
        const __half2* hB = (const __half2*)&rB;
        #pragma unroll
        for (int j = 0; j < 4; ++j) {
            float2 fA = __half22float2(hA[j]);
            float2 fB = __half22float2(hB[j]);
            acc[2 * j]     = fmaf(pA, fA.x, acc[2 * j]);
            acc[2 * j + 1] = fmaf(pA, fA.y, acc[2 * j + 1]);
            acc[2 * j]     = fmaf(pB, fB.x, acc[2 * j]);
            acc[2 * j + 1] = fmaf(pB, fB.y, acc[2 * j + 1]);
        }
    }
    if (k < deg) {
        int s = csr[s0 + k];
        float a = as1[s * NHEAD + head];
        float4 r = h1q[(unsigned)s * 8u + head];
        float p = __expf(lrelu(a + ad));
        den += p;
        const __half2* hh = (const __half2*)&r;
        #pragma unroll
        for (int j = 0; j < 4; ++j) {
            float2 f = __half22float2(hh[j]);
            acc[2 * j]     = fmaf(p, f.x, acc[2 * j]);
            acc[2 * j + 1] = fmaf(p, f.y, acc[2 * j + 1]);
        }
    }

    #pragma unroll
    for (int r = 0; r < 8; ++r) {
        acc[r] += __shfl_xor(acc[r], 8);
        acc[r] += __shfl_xor(acc[r], 16);
        acc[r] += __shfl_xor(acc[r], 32);
    }
    den += __shfl_xor(den, 8);
    den += __shfl_xor(den, 16);
    den += __shfl_xor(den, 32);

    const float4 b0 = ((const float4*)b1)[head * 2];
    const float4 b1v = ((const float4*)b1)[head * 2 + 1];
    const float4 w0 = ((const float4*)W2)[head * 2];
    const float4 w1v = ((const float4*)W2)[head * 2 + 1];
    const float inv = 1.f / den;
    float tt = 0.f;
    tt += fmaxf(fmaf(acc[0], inv, b0.x), 0.f) * w0.x;
    tt += fmaxf(fmaf(acc[1], inv, b0.y), 0.f) * w0.y;
    tt += fmaxf(fmaf(acc[2], inv, b0.z), 0.f) * w0.z;
    tt += fmaxf(fmaf(acc[3], inv, b0.w), 0.f) * w0.w;
    tt += fmaxf(fmaf(acc[4], inv, b1v.x), 0.f) * w1v.x;
    tt += fmaxf(fmaf(acc[5], inv, b1v.y), 0.f) * w1v.y;
    tt += fmaxf(fmaf(acc[6], inv, b1v.z), 0.f) * w1v.z;
    tt += fmaxf(fmaf(acc[7], inv, b1v.w), 0.f) * w1v.w;
    tt += __shfl_xor(tt, 1);
    tt += __shfl_xor(tt, 2);
    tt += __shfl_xor(tt, 4);
    if (lane == 0) h2[n] = tt;
}

// ---------------------------------------------------------------------------
// K6 (fused): layer-2 GAT + mean-pool accumulate. 1024 threads = 16 waves x
// 4 nodes (16 lanes/node) = 64 consecutive nodes per block. Per-node results
// go to LDS; wave 0 does the segmented reduce (batch sorted) and issues
// ~2 atomics/block into cacheline-padded gacc[g*16 + {0,1}].
// ---------------------------------------------------------------------------
__global__ __launch_bounds__(1024) void k_gat2pool(
    const unsigned* __restrict__ offs, const int* __restrict__ csr,
    const float* __restrict__ h2, const int* __restrict__ batch,
    const float* __restrict__ a_src2, const float* __restrict__ a_dst2,
    const float* __restrict__ b2, float* __restrict__ gacc, int N)
{
    __shared__ float vals[64];
    __shared__ int gid[64];
    const int t = threadIdx.x;
    if (t < 64) gid[t] = -1;
    __syncthreads();

    const int lane = t & 63;
    const int ql = lane & 15;
    const int slot = (t >> 6) * 4 + (lane >> 4);     // 0..63 within block
    const int n = blockIdx.x * 64 + slot;

    if (n < N) {
        const float aS = a_src2[0], aD = a_dst2[0];
        const unsigned s0 = offs[n], s1 = offs[n + 1];
        const float ad = h2[n] * aD;
        float num = 0.f, den = 0.f;
        for (unsigned j = s0 + (unsigned)ql; j < s1; j += 16) {
            float hs = h2[csr[j]];
            float p = __expf(lrelu(hs * aS + ad));
            num = fmaf(p, hs, num);
            den += p;
        }
        #pragma unroll
        for (int msk = 1; msk < 16; msk <<= 1) {
            num += __shfl_xor(num, msk);
            den += __shfl_xor(den, msk);
        }
        if (ql == 0) {
            vals[slot] = num / den + b2[0];
            gid[slot] = batch[n];
        }
    }
    __syncthreads();

    if (t < 64) {   // wave 0: segmented reduce over 64 node results
        int g = gid[t];
        float o = (g >= 0) ? vals[t] : 0.f;
        const int g0 = __shfl(g, 0);       // node blockIdx*64 exists (grid sizing)
        const bool same = (g == g0);
        float s = same ? o : 0.f;
        float c = (same && g >= 0) ? 1.f : 0.f;
        #pragma unroll
        for (int msk = 1; msk < 64; msk <<= 1) {
            s += __shfl_xor(s, msk);
            c += __shfl_xor(c, msk);
        }
        if (t == 0) {
            unsafeAtomicAdd(&gacc[g0 * 16], s);
            unsafeAtomicAdd(&gacc[g0 * 16 + 1], c);
        }
        if (g >= 0 && !same) {             // graph boundary inside block (rare)
            unsafeAtomicAdd(&gacc[g * 16], o);
            unsafeAtomicAdd(&gacc[g * 16 + 1], 1.0f);
        }
    }
}

// ---------------------------------------------------------------------------
// K7: final per-graph mean
// ---------------------------------------------------------------------------
__global__ void k_final(const float* __restrict__ gacc,
                        float* __restrict__ out, int G)
{
    int g = blockIdx.x * blockDim.x + threadIdx.x;
    if (g < G) out[g] = gacc[g * 16] / fmaxf(gacc[g * 16 + 1], 1.0f);
}

// ---------------------------------------------------------------------------
extern "C" void kernel_launch(void* const* d_in, const int* in_sizes, int n_in,
                              void* d_out, int out_size, void* d_ws, size_t ws_size,
                              hipStream_t stream)
{
    const float* x      = (const float*)d_in[0];
    const int*   eidx   = (const int*)d_in[1];
    const int*   batch  = (const int*)d_in[2];
    const float* W1     = (const float*)d_in[3];
    const float* a_src1 = (const float*)d_in[4];
    const float* a_dst1 = (const float*)d_in[5];
    const float* b1     = (const float*)d_in[6];
    const float* W2     = (const float*)d_in[7];
    const float* a_src2 = (const float*)d_in[8];
    const float* a_dst2 = (const float*)d_in[9];
    const float* b2     = (const float*)d_in[10];

    const int N = in_sizes[0] / NF;      // 50000
    const int E = in_sizes[1] / 2;       // 1600000
    const int G = out_size;              // 64
    const int ETOT = E + N;
    const int NB = (N + BKT - 1) / BKT;  // 391 buckets
    const int CH = (ETOT + NBLK - 1) / NBLK;
    const int GB = (N + BM - 1) / BM;    // 782 gemm blocks

    // workspace layout (bytes)
    char* w = (char*)d_ws;
    __half*   h1h   = (__half*)(w + 0);           //  6,400,000 (fp16)
    float*    as1   = (float*)(w + 6400000);      //  1,600,000
    float*    ad1   = (float*)(w + 8000000);      //  1,600,000
    float*    h2    = (float*)(w + 9600000);      //    200,000
    unsigned* offs  = (unsigned*)(w + 9800000);   //    200,064
    unsigned* rbuf  = (unsigned*)(w + 10000064);  //  6,600,000 (records -> csr)
    unsigned* M     = (unsigned*)(w + 16600064);  //    400,384 (NB*NBLK)
    unsigned* Bbase = (unsigned*)(w + 17000448);  //      2,048
    float*    gacc  = (float*)(w + 17002496);     //      4,096 (64 graphs x 16)

    k_front<<<GB + NBLK, 256, 0, stream>>>(x, W1, a_src1, a_dst1,
                                           h1h, as1, ad1,
                                           eidx, M, gacc, N, E, GB, NB, CH);
    k_scan2<<<1, 1024, 0, stream>>>(M, Bbase, NB);
    k_bscatter<<<NBLK, 256, 0, stream>>>(eidx, E, N, NB, CH, M, rbuf);
    k_csr<<<NB, 256, 0, stream>>>(Bbase, N, NB, rbuf, offs);

    const int* csr = (const int*)rbuf;
    k_gat1<<<(N + 3) / 4, 256, 0, stream>>>(offs, csr, (const float4*)h1h,
                                            as1, ad1, b1, W2, h2, N);
    k_gat2pool<<<(N + 63) / 64, 1024, 0, stream>>>(offs, csr, h2, batch,
                                                   a_src2, a_dst2, b2, gacc, N);
    k_final<<<1, 64, 0, stream>>>(gacc, (float*)d_out, G);
}